// Round 4
// baseline (1900.100 us; speedup 1.0000x reference)
//
#include <hip/hip_runtime.h>
#include <math.h>

#define FD 64
#define NRBF 20
#define CUT 5.0f
#define EPSV 1e-8f
#define PI_F 3.14159265358979f

__device__ __forceinline__ float wredsum(float v){
#pragma unroll
  for (int m = 32; m >= 1; m >>= 1) v += __shfl_xor(v, m, 64);
  return v;
}
__device__ __forceinline__ float wredmax(float v){
#pragma unroll
  for (int m = 32; m >= 1; m >>= 1) v = fmaxf(v, __shfl_xor(v, m, 64));
  return v;
}
__device__ __forceinline__ float silu_f(float x){ return x * (1.0f / (1.0f + __expf(-x))); }

// ---- K0: per-pair precompute: dir(3), fcut(1), phi*fcut(20) -> 24 floats ----
__global__ __launch_bounds__(256) void k_pairprep(const float* __restrict__ Rij,
                                                  float* __restrict__ pair, int P)
{
  int p = blockIdx.x * blockDim.x + threadIdx.x;
  if (p >= P) return;
  float rx = Rij[3*p+0], ry = Rij[3*p+1], rz = Rij[3*p+2];
  float d = sqrtf(rx*rx + ry*ry + rz*rz);
  float inv = 1.0f / d;
  float fc = (d < CUT) ? 0.5f * (__cosf(PI_F * d / CUT) + 1.0f) : 0.0f;
  float* pr = pair + (size_t)p * 24;
  pr[0] = rx*inv; pr[1] = ry*inv; pr[2] = rz*inv; pr[3] = fc;
  const float width = CUT / (float)(NRBF - 1);
#pragma unroll
  for (int r = 0; r < NRBF; ++r){
    float t = (d - width * (float)r) / width;
    pr[4+r] = __expf(-0.5f * t * t) * fc;
  }
}

// ---- transpose+swizzle rec_W2 -> rW2S[l][c][f][kq^(f&7)][km], rb2 -> rb2T[l][c][f] ----
__global__ __launch_bounds__(256) void k_transpose_w(const float* __restrict__ rW2,
                                                     const float* __restrict__ rb2,
                                                     float* __restrict__ rW2S,
                                                     float* __restrict__ rb2T)
{
  int t = blockIdx.x * blockDim.x + threadIdx.x;
  if (t < 2*64*32*64){
    int km = t & 3;
    int kq = (t >> 2) & 7;
    int f  = (t >> 5) & 63;
    int c  = (t >> 11) & 63;
    int l  = t >> 17;
    int k  = ((kq ^ (f & 7)) << 2) | km;
    rW2S[t] = rW2[((size_t)(l*32 + k))*4096 + f*64 + c];
  }
  if (t < 2*64*64){
    int f = t & 63, c = (t >> 6) & 63, l = t >> 12;
    rb2T[t] = rb2[(size_t)l*4096 + f*64 + c];
  }
}

// ---- K_init: q = embed[Z] ----
__global__ __launch_bounds__(256) void k_init_q(const int* __restrict__ Z,
                                                const float* __restrict__ embed,
                                                float* __restrict__ q, int Ntot)
{
  int t = blockIdx.x * blockDim.x + threadIdx.x;
  if (t >= Ntot * FD) return;
  int n = t >> 6, f = t & 63;
  q[t] = embed[Z[n]*FD + f];
}

// ---- K1: per-atom: X = silu(q@cW1+cb1)@cW2+cb2 ; CV = compress(mu) ----
__global__ __launch_bounds__(256) void k_atom_pre(
    const float* __restrict__ q, const float* __restrict__ mu,
    const float* __restrict__ cW1, const float* __restrict__ cb1,
    const float* __restrict__ cW2, const float* __restrict__ cb2,
    const float* __restrict__ pW1, const float* __restrict__ pb1,
    const float* __restrict__ pW2, const float* __restrict__ pb2,
    float* __restrict__ X, float* __restrict__ CV, int Ntot)
{
  __shared__ float qs[4][64];
  __shared__ float h1[4][64];
  __shared__ float sbuf[4][128];
  __shared__ float hc[4][32];
  int w = threadIdx.x >> 6;
  int f = threadIdx.x & 63;
  int n = blockIdx.x * 4 + w;
  bool ok = (n < Ntot);
  if (!ok) n = Ntot - 1;

  float qv = q[(size_t)n*64 + f];
  qs[w][f] = qv;

  const float* mun = mu + (size_t)n * 384;
  float m0a = mun[0*128 + f],      m1a = mun[1*128 + f],      m2a = mun[2*128 + f];
  float m0b = mun[0*128 + 64 + f], m1b = mun[1*128 + 64 + f], m2b = mun[2*128 + 64 + f];
  sbuf[w][f]      = sqrtf(m0a*m0a + m1a*m1a + m2a*m2a + EPSV);
  sbuf[w][64 + f] = sqrtf(m0b*m0b + m1b*m1b + m2b*m2b + EPSV);

  float acc = cb1[f];
#pragma unroll
  for (int k = 0; k < 64; ++k) acc = fmaf(qs[w][k], cW1[k*64 + f], acc);
  h1[w][f] = silu_f(acc);

  float x0 = cb2[f], x1 = cb2[64+f], x2 = cb2[128+f];
#pragma unroll
  for (int k = 0; k < 64; ++k){
    float h = h1[w][k];
    x0 = fmaf(h, cW2[k*192 + f],       x0);
    x1 = fmaf(h, cW2[k*192 + 64 + f],  x1);
    x2 = fmaf(h, cW2[k*192 + 128 + f], x2);
  }
  if (ok){
    float* Xn = X + (size_t)n*192;
    Xn[f] = x0; Xn[64+f] = x1; Xn[128+f] = x2;
  }

  int ki = f & 31;
  float ah = pb1[ki];
#pragma unroll
  for (int c = 0; c < 128; ++c) ah = fmaf(sbuf[w][c], pW1[c*32 + ki], ah);
  if (f < 32) hc[w][f] = fmaxf(ah, 0.0f);

  float logit = pb2[f];
#pragma unroll
  for (int k = 0; k < 32; ++k) logit = fmaf(hc[w][k], pW2[k*64 + f], logit);
  float mx = wredmax(logit);
  float e  = __expf(logit - mx);
  float se = wredsum(e);
  float wt = e / se;
  float v0 = wredsum(m0a + m0b);
  float v1 = wredsum(m1a + m1b);
  float v2 = wredsum(m2a + m2b);
  if (ok){
    float* cvn = CV + (size_t)n*192;
    cvn[f] = v0 * wt; cvn[64+f] = v1 * wt; cvn[128+f] = v2 * wt;
  }
}

// ---- K2: per-pair: filters on the fly, gather X[j], CV[j], atomic scatter to i ----
__global__ __launch_bounds__(256) void k_edge(
    const float* __restrict__ pair, const int* __restrict__ idx_i, const int* __restrict__ idx_j,
    const float* __restrict__ fW, const float* __restrict__ fb,
    const float* __restrict__ X, const float* __restrict__ CV,
    float* __restrict__ dq, float* __restrict__ dmu, int l, int P)
{
  int w = threadIdx.x >> 6;
  int f = threadIdx.x & 63;
  int p = blockIdx.x * 4 + w;
  if (p >= P) return;
  const float* pr = pair + (size_t)p * 24;
  float d0 = pr[0], d1 = pr[1], d2 = pr[2], fc = pr[3];
  int i = idx_i[p], j = idx_j[p];
  const int col = l * 192;
  float w0 = fb[col + f] * fc, w1 = fb[col + 64 + f] * fc, w2 = fb[col + 128 + f] * fc;
#pragma unroll
  for (int r = 0; r < NRBF; ++r){
    float ph = pr[4 + r];
    const float* fr = fW + r*384 + col;
    w0 = fmaf(ph, fr[f],       w0);
    w1 = fmaf(ph, fr[64 + f],  w1);
    w2 = fmaf(ph, fr[128 + f], w2);
  }
  const float* Xj = X + (size_t)j * 192;
  float dqv = Xj[f]       * w0;
  float dmR = Xj[64 + f]  * w1;
  float dmm = Xj[128 + f] * w2;
  const float* cvj = CV + (size_t)j * 192;
  atomicAdd(&dq[(size_t)i*64 + f], dqv);
  atomicAdd(&dmu[(size_t)i*192 + f],       fmaf(dmR, d0, dmm * cvj[f]));
  atomicAdd(&dmu[(size_t)i*192 + 64 + f],  fmaf(dmR, d1, dmm * cvj[64 + f]));
  atomicAdd(&dmu[(size_t)i*192 + 128 + f], fmaf(dmR, d2, dmm * cvj[128 + f]));
}

// ---- K3: fused post (tv + mixing). 8 atoms/block (2 per wave).
// Phase A: rec MLP + fused tv with LDS-staged swizzled rW2S tiles.
// Phase B: mixing with Wm/mW1/mW2 staged into the same LDS buffer. ----
__global__ __launch_bounds__(256) void k_post(
    float* __restrict__ q, float* __restrict__ mu,
    const float* __restrict__ dq, const float* __restrict__ dmuA, const float* __restrict__ CV,
    const float* __restrict__ rW1, const float* __restrict__ rb1,
    const float* __restrict__ rW2S, const float* __restrict__ rb2Tl,
    const float* __restrict__ mW1, const float* __restrict__ mb1,
    const float* __restrict__ mW2, const float* __restrict__ mb2,
    const float* __restrict__ Wm, int Ntot)
{
  __shared__ float mus[8][3][64];   // 6 KB (wave-private rows)
  __shared__ float svs[8][64];      // 2 KB (reused as h2a in phase B)
  __shared__ float wbuf[16384];     // 64 KB weight stage
  __shared__ float rbt[8][64];      // 2 KB
  __shared__ float avs[8][128];     // 4 KB (wave-private rows)
  int t = threadIdx.x;
  int w = t >> 6, f = t & 63;
  int base = blockIdx.x * 8;
  const int a0 = w*2, a1 = a0 + 1;

  // ---- phase A1: mu_int, s-norm, qn ----
  float qv0, qv1;
#pragma unroll
  for (int s = 0; s < 2; ++s){
    int a = a0 + s;
    int n = base + a; if (n >= Ntot) n = Ntot - 1;
    const float* dmn = dmuA + (size_t)n*192;
    const float* cvn = CV   + (size_t)n*192;
    float m0 = dmn[f]       + cvn[f];
    float m1 = dmn[64 + f]  + cvn[64 + f];
    float m2 = dmn[128 + f] + cvn[128 + f];
    mus[a][0][f] = m0; mus[a][1][f] = m1; mus[a][2][f] = m2;
    svs[a][f] = sqrtf(m0*m0 + m1*m1 + m2*m2 + EPSV);
    float qn = q[(size_t)n*64 + f] + dq[(size_t)n*64 + f];
    if (s == 0) qv0 = qn; else qv1 = qn;
  }
  __syncthreads();

  // ---- phase A2: h (lanes 0-31 -> atom a0, 32-63 -> a1), broadcast to regs ----
  int ki = f & 31;
  int a_h = a0 + (f >> 5);
  float ah = rb1[ki];
#pragma unroll
  for (int c = 0; c < 64; ++c) ah = fmaf(svs[a_h][c], rW1[c*32 + ki], ah);
  ah = fmaxf(ah, 0.0f);
  float hreg[2][32];
#pragma unroll
  for (int k = 0; k < 32; ++k){
    hreg[0][k] = __shfl(ah, k, 64);
    hreg[1][k] = __shfl(ah, 32 + k, 64);
  }

  // ---- phase A3: fused sw/tv over 8 LDS tiles ----
  float mf00 = mus[a0][0][f], mf01 = mus[a0][1][f], mf02 = mus[a0][2][f];
  float mf10 = mus[a1][0][f], mf11 = mus[a1][1][f], mf12 = mus[a1][2][f];
  float tv00=0,tv01=0,tv02=0, tv10=0,tv11=0,tv12=0;
  const int sw8 = (f & 7);
  float4* wt4 = (float4*)wbuf;

  for (int ct = 0; ct < 8; ++ct){
    __syncthreads();
    const float4* src = (const float4*)rW2S + (size_t)ct*4096;
#pragma unroll
    for (int i = 0; i < 16; ++i) wt4[t + i*256] = src[t + i*256];
    if (t < 128) ((float4*)rbt)[t] = ((const float4*)(rb2Tl + ct*512))[t];
    __syncthreads();

#pragma unroll
    for (int cc = 0; cc < 8; ++cc){
      int c = ct*8 + cc;
      float u00 = mus[a0][0][c], u01 = mus[a0][1][c], u02 = mus[a0][2][c];
      float u10 = mus[a1][0][c], u11 = mus[a1][1][c], u12 = mus[a1][2][c];
      float g0 = u00*mf00 + u01*mf01 + u02*mf02;
      float g1 = u10*mf10 + u11*mf11 + u12*mf12;
      float acc0 = rbt[cc][f];
      float acc1 = acc0;
      const float4* wrow = &wt4[(cc*64 + f)*8];
#pragma unroll
      for (int kq = 0; kq < 8; ++kq){
        float4 wv = wrow[kq ^ sw8];
        int k0 = kq*4;
        acc0 = fmaf(hreg[0][k0+0], wv.x, acc0);
        acc0 = fmaf(hreg[0][k0+1], wv.y, acc0);
        acc0 = fmaf(hreg[0][k0+2], wv.z, acc0);
        acc0 = fmaf(hreg[0][k0+3], wv.w, acc0);
        acc1 = fmaf(hreg[1][k0+0], wv.x, acc1);
        acc1 = fmaf(hreg[1][k0+1], wv.y, acc1);
        acc1 = fmaf(hreg[1][k0+2], wv.z, acc1);
        acc1 = fmaf(hreg[1][k0+3], wv.w, acc1);
      }
      float mm0 = acc0 * g0, mm1 = acc1 * g1;
      tv00 = fmaf(u00, mm0, tv00); tv01 = fmaf(u01, mm0, tv01); tv02 = fmaf(u02, mm0, tv02);
      tv10 = fmaf(u10, mm1, tv10); tv11 = fmaf(u11, mm1, tv11); tv12 = fmaf(u12, mm1, tv12);
    }
  }

  // ---- phase B1: stage Wm (64x128 = 32 KB), compute muV/muW for both atoms ----
  __syncthreads();   // everyone done reading last rW2S tile
#pragma unroll
  for (int i = 0; i < 8; ++i) wt4[t + i*256] = ((const float4*)Wm)[t + i*256];
  __syncthreads();

  float V00=0,V01=0,V02=0, W00=0,W01=0,W02=0;   // atom a0
  float V10=0,V11=0,V12=0, W10=0,W11=0,W12=0;   // atom a1
#pragma unroll
  for (int k = 0; k < 64; ++k){
    float wv = wbuf[k*128 + f];
    float ww = wbuf[k*128 + 64 + f];
    float b00 = mus[a0][0][k], b01 = mus[a0][1][k], b02 = mus[a0][2][k];
    float b10 = mus[a1][0][k], b11 = mus[a1][1][k], b12 = mus[a1][2][k];
    V00 = fmaf(b00, wv, V00); V01 = fmaf(b01, wv, V01); V02 = fmaf(b02, wv, V02);
    W00 = fmaf(b00, ww, W00); W01 = fmaf(b01, ww, W01); W02 = fmaf(b02, ww, W02);
    V10 = fmaf(b10, wv, V10); V11 = fmaf(b11, wv, V11); V12 = fmaf(b12, wv, V12);
    W10 = fmaf(b10, ww, W10); W11 = fmaf(b11, ww, W11); W12 = fmaf(b12, ww, W12);
  }
  avs[a0][f] = qv0; avs[a0][64+f] = sqrtf(V00*V00 + V01*V01 + V02*V02 + EPSV);
  avs[a1][f] = qv1; avs[a1][64+f] = sqrtf(V10*V10 + V11*V11 + V12*V12 + EPSV);

  // ---- phase B2: stage mW1 (128x64 = 32 KB), compute h2 for both atoms ----
  __syncthreads();
#pragma unroll
  for (int i = 0; i < 8; ++i) wt4[t + i*256] = ((const float4*)mW1)[t + i*256];
  __syncthreads();

  float a2acc0 = mb1[f], a2acc1 = a2acc0;
#pragma unroll
  for (int k = 0; k < 128; ++k){
    float wv = wbuf[k*64 + f];
    a2acc0 = fmaf(avs[a0][k], wv, a2acc0);
    a2acc1 = fmaf(avs[a1][k], wv, a2acc1);
  }
  float (*h2a)[64] = svs;          // svs dead; rows wave-private
  h2a[a0][f] = silu_f(a2acc0);
  h2a[a1][f] = silu_f(a2acc1);

  // ---- phase B3: stage mW2 (64x192 = 48 KB), compute y for both atoms ----
  __syncthreads();
#pragma unroll
  for (int i = 0; i < 12; ++i) wt4[t + i*256] = ((const float4*)mW2)[t + i*256];
  __syncthreads();

  float y00 = mb2[f], y01 = mb2[64+f], y02 = mb2[128+f];
  float y10 = y00, y11 = y01, y12 = y02;
#pragma unroll
  for (int k = 0; k < 64; ++k){
    float h0 = h2a[a0][k], h1 = h2a[a1][k];
    float w0 = wbuf[k*192 + f];
    float w1 = wbuf[k*192 + 64 + f];
    float w2 = wbuf[k*192 + 128 + f];
    y00 = fmaf(h0, w0, y00); y01 = fmaf(h0, w1, y01); y02 = fmaf(h0, w2, y02);
    y10 = fmaf(h1, w0, y10); y11 = fmaf(h1, w1, y11); y12 = fmaf(h1, w2, y12);
  }

  // ---- write-out ----
  int n0 = base + a0, n1 = base + a1;
  if (n0 < Ntot){
    float dot = V00*W00 + V01*W01 + V02*W02;
    q[(size_t)n0*64 + f] = qv0 + y00 + y02*dot;
    float* mun = mu + (size_t)n0*384;
    mun[0*128 + f] = fmaf(y01, W00, mf00); mun[0*128 + 64 + f] = tv00;
    mun[1*128 + f] = fmaf(y01, W01, mf01); mun[1*128 + 64 + f] = tv01;
    mun[2*128 + f] = fmaf(y01, W02, mf02); mun[2*128 + 64 + f] = tv02;
  }
  if (n1 < Ntot){
    float dot = V10*W10 + V11*W11 + V12*W12;
    q[(size_t)n1*64 + f] = qv1 + y10 + y12*dot;
    float* mun = mu + (size_t)n1*384;
    mun[0*128 + f] = fmaf(y11, W10, mf10); mun[0*128 + 64 + f] = tv10;
    mun[1*128 + f] = fmaf(y11, W11, mf11); mun[1*128 + 64 + f] = tv11;
    mun[2*128 + f] = fmaf(y11, W12, mf12); mun[2*128 + 64 + f] = tv12;
  }
}

extern "C" void kernel_launch(void* const* d_in, const int* in_sizes, int n_in,
                              void* d_out, int out_size, void* d_ws, size_t ws_size,
                              hipStream_t stream)
{
  const int*   Z      = (const int*)  d_in[0];
  const float* Rij    = (const float*)d_in[1];
  const int*   idx_i  = (const int*)  d_in[2];
  const int*   idx_j  = (const int*)  d_in[3];
  const float* embed  = (const float*)d_in[5];
  const float* fW     = (const float*)d_in[6];
  const float* fb     = (const float*)d_in[7];
  const float* ctxW1  = (const float*)d_in[8];
  const float* ctxb1  = (const float*)d_in[9];
  const float* ctxW2  = (const float*)d_in[10];
  const float* ctxb2  = (const float*)d_in[11];
  const float* compW1 = (const float*)d_in[12];
  const float* compb1 = (const float*)d_in[13];
  const float* compW2 = (const float*)d_in[14];
  const float* compb2 = (const float*)d_in[15];
  const float* recW1  = (const float*)d_in[16];
  const float* recb1  = (const float*)d_in[17];
  const float* recW2  = (const float*)d_in[18];
  const float* recb2  = (const float*)d_in[19];
  const float* mixW1  = (const float*)d_in[20];
  const float* mixb1  = (const float*)d_in[21];
  const float* mixW2  = (const float*)d_in[22];
  const float* mixb2  = (const float*)d_in[23];
  const float* muMixW = (const float*)d_in[24];

  const int N = in_sizes[0];
  const int P = in_sizes[1] / 3;

  float* ws    = (float*)d_ws;
  float* pair  = ws;                         // P*24
  float* q     = pair  + (size_t)P*24;       // N*64
  float* mu    = q     + (size_t)N*64;       // N*384
  float* X     = mu    + (size_t)N*384;      // N*192
  float* CV    = X     + (size_t)N*192;      // N*192
  float* dq    = CV    + (size_t)N*192;      // N*64
  float* dmu   = dq    + (size_t)N*64;       // N*192
  float* rW2S  = dmu   + (size_t)N*192;      // 262144
  float* rb2T  = rW2S  + (size_t)262144;     // 8192

  k_pairprep<<<(P + 255)/256, 256, 0, stream>>>(Rij, pair, P);
  k_transpose_w<<<(262144 + 255)/256, 256, 0, stream>>>(recW2, recb2, rW2S, rb2T);
  hipMemsetAsync(mu, 0, (size_t)N*384*sizeof(float), stream);
  k_init_q<<<(N*FD + 255)/256, 256, 0, stream>>>(Z, embed, q, N);

  const int ablk4 = (N + 3) / 4;
  const int ablk8 = (N + 7) / 8;
  const int pblk  = (P + 3) / 4;
  for (int l = 0; l < 2; ++l){
    hipMemsetAsync(dq,  0, (size_t)N*64 *sizeof(float), stream);
    hipMemsetAsync(dmu, 0, (size_t)N*192*sizeof(float), stream);
    k_atom_pre<<<ablk4, 256, 0, stream>>>(q, mu,
        ctxW1 + (size_t)l*64*64,  ctxb1 + (size_t)l*64,
        ctxW2 + (size_t)l*64*192, ctxb2 + (size_t)l*192,
        compW1 + (size_t)l*128*32, compb1 + (size_t)l*32,
        compW2 + (size_t)l*32*64,  compb2 + (size_t)l*64,
        X, CV, N);
    k_edge<<<pblk, 256, 0, stream>>>(pair, idx_i, idx_j, fW, fb, X, CV, dq, dmu, l, P);
    k_post<<<ablk8, 256, 0, stream>>>(q, mu, dq, dmu, CV,
        recW1 + (size_t)l*64*32, recb1 + (size_t)l*32,
        rW2S + (size_t)l*131072, rb2T + (size_t)l*4096,
        mixW1 + (size_t)l*128*64, mixb1 + (size_t)l*64,
        mixW2 + (size_t)l*64*192, mixb2 + (size_t)l*192,
        muMixW + (size_t)l*64*128, N);
  }

  hipMemcpyAsync(d_out, q, (size_t)N*64*sizeof(float), hipMemcpyDeviceToDevice, stream);
  hipMemcpyAsync((float*)d_out + (size_t)N*64, mu, (size_t)N*384*sizeof(float),
                 hipMemcpyDeviceToDevice, stream);
}

// Round 5
// 1041.094 us; speedup vs baseline: 1.8251x; 1.8251x over previous
//
#include <hip/hip_runtime.h>
#include <math.h>

#define FD 64
#define NRBF 20
#define CUT 5.0f
#define EPSV 1e-8f
#define PI_F 3.14159265358979f

__device__ __forceinline__ float wredsum(float v){
#pragma unroll
  for (int m = 32; m >= 1; m >>= 1) v += __shfl_xor(v, m, 64);
  return v;
}
__device__ __forceinline__ float wredmax(float v){
#pragma unroll
  for (int m = 32; m >= 1; m >>= 1) v = fmaxf(v, __shfl_xor(v, m, 64));
  return v;
}
__device__ __forceinline__ float silu_f(float x){ return x * (1.0f / (1.0f + __expf(-x))); }

// ---- K0: per-pair precompute: dir(3), fcut(1), phi*fcut(20) -> 24 floats ----
__global__ __launch_bounds__(256) void k_pairprep(const float* __restrict__ Rij,
                                                  float* __restrict__ pair, int P)
{
  int p = blockIdx.x * blockDim.x + threadIdx.x;
  if (p >= P) return;
  float rx = Rij[3*p+0], ry = Rij[3*p+1], rz = Rij[3*p+2];
  float d = sqrtf(rx*rx + ry*ry + rz*rz);
  float inv = 1.0f / d;
  float fc = (d < CUT) ? 0.5f * (__cosf(PI_F * d / CUT) + 1.0f) : 0.0f;
  float* pr = pair + (size_t)p * 24;
  pr[0] = rx*inv; pr[1] = ry*inv; pr[2] = rz*inv; pr[3] = fc;
  const float width = CUT / (float)(NRBF - 1);
#pragma unroll
  for (int r = 0; r < NRBF; ++r){
    float t = (d - width * (float)r) / width;
    pr[4+r] = __expf(-0.5f * t * t) * fc;
  }
}

// ---- transpose+swizzle rec_W2 -> rW2S[l][c][f][kq^(f&7)][km], rb2 -> rb2T[l][c][f] ----
__global__ __launch_bounds__(256) void k_transpose_w(const float* __restrict__ rW2,
                                                     const float* __restrict__ rb2,
                                                     float* __restrict__ rW2S,
                                                     float* __restrict__ rb2T)
{
  int t = blockIdx.x * blockDim.x + threadIdx.x;
  if (t < 2*64*32*64){
    int km = t & 3;
    int kq = (t >> 2) & 7;
    int f  = (t >> 5) & 63;
    int c  = (t >> 11) & 63;
    int l  = t >> 17;
    int k  = ((kq ^ (f & 7)) << 2) | km;
    rW2S[t] = rW2[((size_t)(l*32 + k))*4096 + f*64 + c];
  }
  if (t < 2*64*64){
    int f = t & 63, c = (t >> 6) & 63, l = t >> 12;
    rb2T[t] = rb2[(size_t)l*4096 + f*64 + c];
  }
}

// ---- K_init: q = embed[Z] ----
__global__ __launch_bounds__(256) void k_init_q(const int* __restrict__ Z,
                                                const float* __restrict__ embed,
                                                float* __restrict__ q, int Ntot)
{
  int t = blockIdx.x * blockDim.x + threadIdx.x;
  if (t >= Ntot * FD) return;
  int n = t >> 6, f = t & 63;
  q[t] = embed[Z[n]*FD + f];
}

// ---- K1: per-atom: X = silu(q@cW1+cb1)@cW2+cb2 ; CV = compress(mu) ----
__global__ __launch_bounds__(256) void k_atom_pre(
    const float* __restrict__ q, const float* __restrict__ mu,
    const float* __restrict__ cW1, const float* __restrict__ cb1,
    const float* __restrict__ cW2, const float* __restrict__ cb2,
    const float* __restrict__ pW1, const float* __restrict__ pb1,
    const float* __restrict__ pW2, const float* __restrict__ pb2,
    float* __restrict__ X, float* __restrict__ CV, int Ntot)
{
  __shared__ float qs[4][64];
  __shared__ float h1[4][64];
  __shared__ float sbuf[4][128];
  __shared__ float hc[4][32];
  int w = threadIdx.x >> 6;
  int f = threadIdx.x & 63;
  int n = blockIdx.x * 4 + w;
  bool ok = (n < Ntot);
  if (!ok) n = Ntot - 1;

  float qv = q[(size_t)n*64 + f];
  qs[w][f] = qv;

  const float* mun = mu + (size_t)n * 384;
  float m0a = mun[0*128 + f],      m1a = mun[1*128 + f],      m2a = mun[2*128 + f];
  float m0b = mun[0*128 + 64 + f], m1b = mun[1*128 + 64 + f], m2b = mun[2*128 + 64 + f];
  sbuf[w][f]      = sqrtf(m0a*m0a + m1a*m1a + m2a*m2a + EPSV);
  sbuf[w][64 + f] = sqrtf(m0b*m0b + m1b*m1b + m2b*m2b + EPSV);

  float acc = cb1[f];
#pragma unroll
  for (int k = 0; k < 64; ++k) acc = fmaf(qs[w][k], cW1[k*64 + f], acc);
  h1[w][f] = silu_f(acc);

  float x0 = cb2[f], x1 = cb2[64+f], x2 = cb2[128+f];
#pragma unroll
  for (int k = 0; k < 64; ++k){
    float h = h1[w][k];
    x0 = fmaf(h, cW2[k*192 + f],       x0);
    x1 = fmaf(h, cW2[k*192 + 64 + f],  x1);
    x2 = fmaf(h, cW2[k*192 + 128 + f], x2);
  }
  if (ok){
    float* Xn = X + (size_t)n*192;
    Xn[f] = x0; Xn[64+f] = x1; Xn[128+f] = x2;
  }

  int ki = f & 31;
  float ah = pb1[ki];
#pragma unroll
  for (int c = 0; c < 128; ++c) ah = fmaf(sbuf[w][c], pW1[c*32 + ki], ah);
  if (f < 32) hc[w][f] = fmaxf(ah, 0.0f);

  float logit = pb2[f];
#pragma unroll
  for (int k = 0; k < 32; ++k) logit = fmaf(hc[w][k], pW2[k*64 + f], logit);
  float mx = wredmax(logit);
  float e  = __expf(logit - mx);
  float se = wredsum(e);
  float wt = e / se;
  float v0 = wredsum(m0a + m0b);
  float v1 = wredsum(m1a + m1b);
  float v2 = wredsum(m2a + m2b);
  if (ok){
    float* cvn = CV + (size_t)n*192;
    cvn[f] = v0 * wt; cvn[64+f] = v1 * wt; cvn[128+f] = v2 * wt;
  }
}

// ---- K2: per-pair: filters on the fly, gather X[j], CV[j], atomic scatter to i ----
__global__ __launch_bounds__(256) void k_edge(
    const float* __restrict__ pair, const int* __restrict__ idx_i, const int* __restrict__ idx_j,
    const float* __restrict__ fW, const float* __restrict__ fb,
    const float* __restrict__ X, const float* __restrict__ CV,
    float* __restrict__ dq, float* __restrict__ dmu, int l, int P)
{
  int w = threadIdx.x >> 6;
  int f = threadIdx.x & 63;
  int p = blockIdx.x * 4 + w;
  if (p >= P) return;
  const float* pr = pair + (size_t)p * 24;
  float d0 = pr[0], d1 = pr[1], d2 = pr[2], fc = pr[3];
  int i = idx_i[p], j = idx_j[p];
  const int col = l * 192;
  float w0 = fb[col + f] * fc, w1 = fb[col + 64 + f] * fc, w2 = fb[col + 128 + f] * fc;
#pragma unroll
  for (int r = 0; r < NRBF; ++r){
    float ph = pr[4 + r];
    const float* fr = fW + r*384 + col;
    w0 = fmaf(ph, fr[f],       w0);
    w1 = fmaf(ph, fr[64 + f],  w1);
    w2 = fmaf(ph, fr[128 + f], w2);
  }
  const float* Xj = X + (size_t)j * 192;
  float dqv = Xj[f]       * w0;
  float dmR = Xj[64 + f]  * w1;
  float dmm = Xj[128 + f] * w2;
  const float* cvj = CV + (size_t)j * 192;
  atomicAdd(&dq[(size_t)i*64 + f], dqv);
  atomicAdd(&dmu[(size_t)i*192 + f],       fmaf(dmR, d0, dmm * cvj[f]));
  atomicAdd(&dmu[(size_t)i*192 + 64 + f],  fmaf(dmR, d1, dmm * cvj[64 + f]));
  atomicAdd(&dmu[(size_t)i*192 + 128 + f], fmaf(dmR, d2, dmm * cvj[128 + f]));
}

// ---- K3a: tv only. 8 atoms/block (2 per wave). Weight tiles staged in LDS. ----
__global__ __launch_bounds__(256) void k_tv(
    const float* __restrict__ dmuA, const float* __restrict__ CV,
    const float* __restrict__ rW1, const float* __restrict__ rb1,
    const float* __restrict__ rW2S, const float* __restrict__ rb2Tl,
    float* __restrict__ MUI, float* __restrict__ TV, int Ntot)
{
  __shared__ float mus[8][3][64];   // 6 KB
  __shared__ float svs[8][64];      // 2 KB
  __shared__ float4 wt4[4096];      // 64 KB: 8 c x 64 f x 8 float4
  __shared__ float rbt[8][64];      // 2 KB
  int t = threadIdx.x;
  int w = t >> 6, f = t & 63;
  int base = blockIdx.x * 8;

#pragma unroll
  for (int s = 0; s < 2; ++s){
    int a = w*2 + s;
    int n = base + a; bool ok = (n < Ntot); if (!ok) n = Ntot - 1;
    const float* dmn = dmuA + (size_t)n*192;
    const float* cvn = CV   + (size_t)n*192;
    float m0 = dmn[f]       + cvn[f];
    float m1 = dmn[64 + f]  + cvn[64 + f];
    float m2 = dmn[128 + f] + cvn[128 + f];
    mus[a][0][f] = m0; mus[a][1][f] = m1; mus[a][2][f] = m2;
    svs[a][f] = sqrtf(m0*m0 + m1*m1 + m2*m2 + EPSV);
    if (ok){
      float* mo = MUI + (size_t)n*192;
      mo[f] = m0; mo[64+f] = m1; mo[128+f] = m2;
    }
  }
  __syncthreads();

  int ki = f & 31;
  int a_h = w*2 + (f >> 5);
  float ah = rb1[ki];
#pragma unroll
  for (int c = 0; c < 64; ++c) ah = fmaf(svs[a_h][c], rW1[c*32 + ki], ah);
  ah = fmaxf(ah, 0.0f);
  float hreg[2][32];
#pragma unroll
  for (int k = 0; k < 32; ++k){
    hreg[0][k] = __shfl(ah, k, 64);
    hreg[1][k] = __shfl(ah, 32 + k, 64);
  }

  const int a0 = w*2, a1 = a0 + 1;
  float mf00 = mus[a0][0][f], mf01 = mus[a0][1][f], mf02 = mus[a0][2][f];
  float mf10 = mus[a1][0][f], mf11 = mus[a1][1][f], mf12 = mus[a1][2][f];
  float tv00=0,tv01=0,tv02=0, tv10=0,tv11=0,tv12=0;
  const int sw8 = (f & 7);

  for (int ct = 0; ct < 8; ++ct){
    __syncthreads();
    const float4* src = (const float4*)rW2S + (size_t)ct*4096;
#pragma unroll
    for (int i = 0; i < 16; ++i) wt4[t + i*256] = src[t + i*256];
    if (t < 128) ((float4*)rbt)[t] = ((const float4*)(rb2Tl + ct*512))[t];
    __syncthreads();

#pragma unroll
    for (int cc = 0; cc < 8; ++cc){
      int c = ct*8 + cc;
      float u00 = mus[a0][0][c], u01 = mus[a0][1][c], u02 = mus[a0][2][c];
      float u10 = mus[a1][0][c], u11 = mus[a1][1][c], u12 = mus[a1][2][c];
      float g0 = u00*mf00 + u01*mf01 + u02*mf02;
      float g1 = u10*mf10 + u11*mf11 + u12*mf12;
      float acc0 = rbt[cc][f];
      float acc1 = acc0;
      const float4* wrow = &wt4[(cc*64 + f)*8];
#pragma unroll
      for (int kq = 0; kq < 8; ++kq){
        float4 wv = wrow[kq ^ sw8];
        int k0 = kq*4;
        acc0 = fmaf(hreg[0][k0+0], wv.x, acc0);
        acc0 = fmaf(hreg[0][k0+1], wv.y, acc0);
        acc0 = fmaf(hreg[0][k0+2], wv.z, acc0);
        acc0 = fmaf(hreg[0][k0+3], wv.w, acc0);
        acc1 = fmaf(hreg[1][k0+0], wv.x, acc1);
        acc1 = fmaf(hreg[1][k0+1], wv.y, acc1);
        acc1 = fmaf(hreg[1][k0+2], wv.z, acc1);
        acc1 = fmaf(hreg[1][k0+3], wv.w, acc1);
      }
      float mm0 = acc0 * g0, mm1 = acc1 * g1;
      tv00 = fmaf(u00, mm0, tv00); tv01 = fmaf(u01, mm0, tv01); tv02 = fmaf(u02, mm0, tv02);
      tv10 = fmaf(u10, mm1, tv10); tv11 = fmaf(u11, mm1, tv11); tv12 = fmaf(u12, mm1, tv12);
    }
  }

  int n0 = base + a0, n1 = base + a1;
  if (n0 < Ntot){
    float* tvp = TV + (size_t)n0*192;
    tvp[f] = tv00; tvp[64+f] = tv01; tvp[128+f] = tv02;
  }
  if (n1 < Ntot){
    float* tvp = TV + (size_t)n1*192;
    tvp[f] = tv10; tvp[64+f] = tv11; tvp[128+f] = tv12;
  }
}

// ---- K3b v2: mixing tail. 16 atoms/block (4 per wave), weights LDS-staged in
// 3 phases (Wm 32K, mW1 32K, mW2 48K) into one 48 KB buffer. Low-register. ----
__global__ __launch_bounds__(256) void k_mix2(
    float* __restrict__ q, float* __restrict__ mu,
    const float* __restrict__ dq, const float* __restrict__ MUI, const float* __restrict__ TV,
    const float* __restrict__ mW1, const float* __restrict__ mb1,
    const float* __restrict__ mW2, const float* __restrict__ mb2,
    const float* __restrict__ Wm, int Ntot)
{
  __shared__ float wbuf[12288];     // 48 KB
  __shared__ float mua[16][3][64];  // 12 KB
  __shared__ float ava[16][128];    // 8 KB
  __shared__ float h2a[16][64];     // 4 KB
  int t = threadIdx.x;
  int w = t >> 6, f = t & 63;
  int base = blockIdx.x * 16;
  const int aw = w * 4;
  float4* wt4 = (float4*)wbuf;

  float qv[4], m0[4], m1[4], m2[4];
#pragma unroll
  for (int s = 0; s < 4; ++s){
    int a = aw + s;
    int n = base + a; if (n >= Ntot) n = Ntot - 1;
    qv[s] = q[(size_t)n*64 + f] + dq[(size_t)n*64 + f];
    const float* mi = MUI + (size_t)n*192;
    m0[s] = mi[f]; m1[s] = mi[64 + f]; m2[s] = mi[128 + f];
    mua[a][0][f] = m0[s]; mua[a][1][f] = m1[s]; mua[a][2][f] = m2[s];
  }

  // ---- stage Wm (64x128 = 32 KB) ----
#pragma unroll
  for (int i = 0; i < 8; ++i) wt4[t + i*256] = ((const float4*)Wm)[t + i*256];
  __syncthreads();

  float V0[4]={0,0,0,0}, V1[4]={0,0,0,0}, V2[4]={0,0,0,0};
  float W0[4]={0,0,0,0}, W1[4]={0,0,0,0}, W2[4]={0,0,0,0};
  for (int k = 0; k < 64; ++k){
    float wv = wbuf[k*128 + f];
    float ww = wbuf[k*128 + 64 + f];
#pragma unroll
    for (int s = 0; s < 4; ++s){
      int a = aw + s;
      float b0 = mua[a][0][k], b1 = mua[a][1][k], b2 = mua[a][2][k];
      V0[s] = fmaf(b0, wv, V0[s]); V1[s] = fmaf(b1, wv, V1[s]); V2[s] = fmaf(b2, wv, V2[s]);
      W0[s] = fmaf(b0, ww, W0[s]); W1[s] = fmaf(b1, ww, W1[s]); W2[s] = fmaf(b2, ww, W2[s]);
    }
  }
  float dot[4];
#pragma unroll
  for (int s = 0; s < 4; ++s){
    int a = aw + s;
    ava[a][f] = qv[s];
    ava[a][64 + f] = sqrtf(V0[s]*V0[s] + V1[s]*V1[s] + V2[s]*V2[s] + EPSV);
    dot[s] = V0[s]*W0[s] + V1[s]*W1[s] + V2[s]*W2[s];
  }

  // ---- stage mW1 (128x64 = 32 KB) ----
  __syncthreads();
#pragma unroll
  for (int i = 0; i < 8; ++i) wt4[t + i*256] = ((const float4*)mW1)[t + i*256];
  __syncthreads();

  float acc[4];
#pragma unroll
  for (int s = 0; s < 4; ++s) acc[s] = mb1[f];
  for (int k = 0; k < 128; ++k){
    float wv = wbuf[k*64 + f];
#pragma unroll
    for (int s = 0; s < 4; ++s) acc[s] = fmaf(ava[aw + s][k], wv, acc[s]);
  }
#pragma unroll
  for (int s = 0; s < 4; ++s) h2a[aw + s][f] = silu_f(acc[s]);

  // ---- stage mW2 (64x192 = 48 KB) ----
  __syncthreads();
#pragma unroll
  for (int i = 0; i < 12; ++i) wt4[t + i*256] = ((const float4*)mW2)[t + i*256];
  __syncthreads();

  float y0[4], y1[4], y2[4];
#pragma unroll
  for (int s = 0; s < 4; ++s){ y0[s] = mb2[f]; y1[s] = mb2[64+f]; y2[s] = mb2[128+f]; }
  for (int k = 0; k < 64; ++k){
    float u0 = wbuf[k*192 + f];
    float u1 = wbuf[k*192 + 64 + f];
    float u2 = wbuf[k*192 + 128 + f];
#pragma unroll
    for (int s = 0; s < 4; ++s){
      float h = h2a[aw + s][k];
      y0[s] = fmaf(h, u0, y0[s]); y1[s] = fmaf(h, u1, y1[s]); y2[s] = fmaf(h, u2, y2[s]);
    }
  }

#pragma unroll
  for (int s = 0; s < 4; ++s){
    int n = base + aw + s;
    if (n < Ntot){
      q[(size_t)n*64 + f] = qv[s] + y0[s] + y2[s]*dot[s];
      const float* tvp = TV + (size_t)n*192;
      float* mun = mu + (size_t)n*384;
      mun[0*128 + f] = fmaf(y1[s], W0[s], m0[s]); mun[0*128 + 64 + f] = tvp[f];
      mun[1*128 + f] = fmaf(y1[s], W1[s], m1[s]); mun[1*128 + 64 + f] = tvp[64+f];
      mun[2*128 + f] = fmaf(y1[s], W2[s], m2[s]); mun[2*128 + 64 + f] = tvp[128+f];
    }
  }
}

extern "C" void kernel_launch(void* const* d_in, const int* in_sizes, int n_in,
                              void* d_out, int out_size, void* d_ws, size_t ws_size,
                              hipStream_t stream)
{
  const int*   Z      = (const int*)  d_in[0];
  const float* Rij    = (const float*)d_in[1];
  const int*   idx_i  = (const int*)  d_in[2];
  const int*   idx_j  = (const int*)  d_in[3];
  const float* embed  = (const float*)d_in[5];
  const float* fW     = (const float*)d_in[6];
  const float* fb     = (const float*)d_in[7];
  const float* ctxW1  = (const float*)d_in[8];
  const float* ctxb1  = (const float*)d_in[9];
  const float* ctxW2  = (const float*)d_in[10];
  const float* ctxb2  = (const float*)d_in[11];
  const float* compW1 = (const float*)d_in[12];
  const float* compb1 = (const float*)d_in[13];
  const float* compW2 = (const float*)d_in[14];
  const float* compb2 = (const float*)d_in[15];
  const float* recW1  = (const float*)d_in[16];
  const float* recb1  = (const float*)d_in[17];
  const float* recW2  = (const float*)d_in[18];
  const float* recb2  = (const float*)d_in[19];
  const float* mixW1  = (const float*)d_in[20];
  const float* mixb1  = (const float*)d_in[21];
  const float* mixW2  = (const float*)d_in[22];
  const float* mixb2  = (const float*)d_in[23];
  const float* muMixW = (const float*)d_in[24];

  const int N = in_sizes[0];
  const int P = in_sizes[1] / 3;

  float* ws    = (float*)d_ws;
  float* pair  = ws;                         // P*24
  float* q     = pair  + (size_t)P*24;       // N*64
  float* mu    = q     + (size_t)N*64;       // N*384
  float* X     = mu    + (size_t)N*384;      // N*192  (reused as MUI after k_edge)
  float* CV    = X     + (size_t)N*192;      // N*192
  float* dq    = CV    + (size_t)N*192;      // N*64
  float* dmu   = dq    + (size_t)N*64;       // N*192
  float* rW2S  = dmu   + (size_t)N*192;      // 262144
  float* rb2T  = rW2S  + (size_t)262144;     // 8192
  float* TV    = rb2T  + (size_t)8192;       // N*192
  float* MUI   = X;                          // overlay: X dead after k_edge

  k_pairprep<<<(P + 255)/256, 256, 0, stream>>>(Rij, pair, P);
  k_transpose_w<<<(262144 + 255)/256, 256, 0, stream>>>(recW2, recb2, rW2S, rb2T);
  hipMemsetAsync(mu, 0, (size_t)N*384*sizeof(float), stream);
  k_init_q<<<(N*FD + 255)/256, 256, 0, stream>>>(Z, embed, q, N);

  const int ablk4  = (N + 3) / 4;
  const int ablk8  = (N + 7) / 8;
  const int ablk16 = (N + 15) / 16;
  const int pblk   = (P + 3) / 4;
  for (int l = 0; l < 2; ++l){
    hipMemsetAsync(dq,  0, (size_t)N*64 *sizeof(float), stream);
    hipMemsetAsync(dmu, 0, (size_t)N*192*sizeof(float), stream);
    k_atom_pre<<<ablk4, 256, 0, stream>>>(q, mu,
        ctxW1 + (size_t)l*64*64,  ctxb1 + (size_t)l*64,
        ctxW2 + (size_t)l*64*192, ctxb2 + (size_t)l*192,
        compW1 + (size_t)l*128*32, compb1 + (size_t)l*32,
        compW2 + (size_t)l*32*64,  compb2 + (size_t)l*64,
        X, CV, N);
    k_edge<<<pblk, 256, 0, stream>>>(pair, idx_i, idx_j, fW, fb, X, CV, dq, dmu, l, P);
    k_tv<<<ablk8, 256, 0, stream>>>(dmu, CV,
        recW1 + (size_t)l*64*32, recb1 + (size_t)l*32,
        rW2S + (size_t)l*131072, rb2T + (size_t)l*4096,
        MUI, TV, N);
    k_mix2<<<ablk16, 256, 0, stream>>>(q, mu, dq, MUI, TV,
        mixW1 + (size_t)l*128*64, mixb1 + (size_t)l*64,
        mixW2 + (size_t)l*64*192, mixb2 + (size_t)l*192,
        muMixW + (size_t)l*64*128, N);
  }

  hipMemcpyAsync(d_out, q, (size_t)N*64*sizeof(float), hipMemcpyDeviceToDevice, stream);
  hipMemcpyAsync((float*)d_out + (size_t)N*64, mu, (size_t)N*384*sizeof(float),
                 hipMemcpyDeviceToDevice, stream);
}

// Round 6
// 768.854 us; speedup vs baseline: 2.4713x; 1.3541x over previous
//
#include <hip/hip_runtime.h>
#include <math.h>

#define FD 64
#define NRBF 20
#define CUT 5.0f
#define EPSV 1e-8f
#define PI_F 3.14159265358979f

__device__ __forceinline__ float wredsum(float v){
#pragma unroll
  for (int m = 32; m >= 1; m >>= 1) v += __shfl_xor(v, m, 64);
  return v;
}
__device__ __forceinline__ float wredmax(float v){
#pragma unroll
  for (int m = 32; m >= 1; m >>= 1) v = fmaxf(v, __shfl_xor(v, m, 64));
  return v;
}
__device__ __forceinline__ float silu_f(float x){ return x * (1.0f / (1.0f + __expf(-x))); }

// ---- K0: per-pair precompute: dir(3), fcut(1), phi*fcut(20) -> 24 floats ----
__global__ __launch_bounds__(256) void k_pairprep(const float* __restrict__ Rij,
                                                  float* __restrict__ pair, int P)
{
  int p = blockIdx.x * blockDim.x + threadIdx.x;
  if (p >= P) return;
  float rx = Rij[3*p+0], ry = Rij[3*p+1], rz = Rij[3*p+2];
  float d = sqrtf(rx*rx + ry*ry + rz*rz);
  float inv = 1.0f / d;
  float fc = (d < CUT) ? 0.5f * (__cosf(PI_F * d / CUT) + 1.0f) : 0.0f;
  float* pr = pair + (size_t)p * 24;
  pr[0] = rx*inv; pr[1] = ry*inv; pr[2] = rz*inv; pr[3] = fc;
  const float width = CUT / (float)(NRBF - 1);
#pragma unroll
  for (int r = 0; r < NRBF; ++r){
    float t = (d - width * (float)r) / width;
    pr[4+r] = __expf(-0.5f * t * t) * fc;
  }
}

// ---- CSR build: histogram, scan, scatter ----
__global__ __launch_bounds__(256) void k_count(const int* __restrict__ idx_i,
                                               int* __restrict__ cnt, int P)
{
  int p = blockIdx.x * blockDim.x + threadIdx.x;
  if (p < P) atomicAdd(&cnt[idx_i[p]], 1);
}

__global__ __launch_bounds__(1024) void k_scan(const int* __restrict__ cnt,
                                               int* __restrict__ start,
                                               int* __restrict__ cursor, int N)
{
  __shared__ int part[1024];
  int t = threadIdx.x;
  int chunk = (N + 1023) / 1024;
  int lo = t * chunk, hi = lo + chunk; if (hi > N) hi = N;
  int s = 0;
  for (int i = lo; i < hi; ++i) s += cnt[i];
  part[t] = s;
  __syncthreads();
  for (int off = 1; off < 1024; off <<= 1){
    int v = 0;
    if (t >= off) v = part[t - off];
    __syncthreads();
    if (t >= off) part[t] += v;
    __syncthreads();
  }
  int run = (t == 0) ? 0 : part[t-1];
  for (int i = lo; i < hi; ++i){ start[i] = run; cursor[i] = run; run += cnt[i]; }
  if (t == 1023) start[N] = run;
}

__global__ __launch_bounds__(256) void k_scatter(const int* __restrict__ idx_i,
                                                 int* __restrict__ cursor,
                                                 int* __restrict__ elist, int P)
{
  int p = blockIdx.x * blockDim.x + threadIdx.x;
  if (p < P){
    int pos = atomicAdd(&cursor[idx_i[p]], 1);
    elist[pos] = p;
  }
}

// ---- transpose+swizzle rec_W2 -> rW2S[l][c][f][kq^(f&7)][km], rb2 -> rb2T[l][c][f] ----
__global__ __launch_bounds__(256) void k_transpose_w(const float* __restrict__ rW2,
                                                     const float* __restrict__ rb2,
                                                     float* __restrict__ rW2S,
                                                     float* __restrict__ rb2T)
{
  int t = blockIdx.x * blockDim.x + threadIdx.x;
  if (t < 2*64*32*64){
    int km = t & 3;
    int kq = (t >> 2) & 7;
    int f  = (t >> 5) & 63;
    int c  = (t >> 11) & 63;
    int l  = t >> 17;
    int k  = ((kq ^ (f & 7)) << 2) | km;
    rW2S[t] = rW2[((size_t)(l*32 + k))*4096 + f*64 + c];
  }
  if (t < 2*64*64){
    int f = t & 63, c = (t >> 6) & 63, l = t >> 12;
    rb2T[t] = rb2[(size_t)l*4096 + f*64 + c];
  }
}

// ---- K_init: q = embed[Z] ----
__global__ __launch_bounds__(256) void k_init_q(const int* __restrict__ Z,
                                                const float* __restrict__ embed,
                                                float* __restrict__ q, int Ntot)
{
  int t = blockIdx.x * blockDim.x + threadIdx.x;
  if (t >= Ntot * FD) return;
  int n = t >> 6, f = t & 63;
  q[t] = embed[Z[n]*FD + f];
}

// ---- K1: per-atom: XCV[n][0..191] = X, XCV[n][192..383] = compress(mu) ----
__global__ __launch_bounds__(256) void k_atom_pre(
    const float* __restrict__ q, const float* __restrict__ mu,
    const float* __restrict__ cW1, const float* __restrict__ cb1,
    const float* __restrict__ cW2, const float* __restrict__ cb2,
    const float* __restrict__ pW1, const float* __restrict__ pb1,
    const float* __restrict__ pW2, const float* __restrict__ pb2,
    float* __restrict__ XCV, int Ntot)
{
  __shared__ float qs[4][64];
  __shared__ float h1[4][64];
  __shared__ float sbuf[4][128];
  __shared__ float hc[4][32];
  int w = threadIdx.x >> 6;
  int f = threadIdx.x & 63;
  int n = blockIdx.x * 4 + w;
  bool ok = (n < Ntot);
  if (!ok) n = Ntot - 1;

  float qv = q[(size_t)n*64 + f];
  qs[w][f] = qv;

  const float* mun = mu + (size_t)n * 384;
  float m0a = mun[0*128 + f],      m1a = mun[1*128 + f],      m2a = mun[2*128 + f];
  float m0b = mun[0*128 + 64 + f], m1b = mun[1*128 + 64 + f], m2b = mun[2*128 + 64 + f];
  sbuf[w][f]      = sqrtf(m0a*m0a + m1a*m1a + m2a*m2a + EPSV);
  sbuf[w][64 + f] = sqrtf(m0b*m0b + m1b*m1b + m2b*m2b + EPSV);

  float acc = cb1[f];
#pragma unroll
  for (int k = 0; k < 64; ++k) acc = fmaf(qs[w][k], cW1[k*64 + f], acc);
  h1[w][f] = silu_f(acc);

  float x0 = cb2[f], x1 = cb2[64+f], x2 = cb2[128+f];
#pragma unroll
  for (int k = 0; k < 64; ++k){
    float h = h1[w][k];
    x0 = fmaf(h, cW2[k*192 + f],       x0);
    x1 = fmaf(h, cW2[k*192 + 64 + f],  x1);
    x2 = fmaf(h, cW2[k*192 + 128 + f], x2);
  }
  if (ok){
    float* Xn = XCV + (size_t)n*384;
    Xn[f] = x0; Xn[64+f] = x1; Xn[128+f] = x2;
  }

  int ki = f & 31;
  float ah = pb1[ki];
#pragma unroll
  for (int c = 0; c < 128; ++c) ah = fmaf(sbuf[w][c], pW1[c*32 + ki], ah);
  if (f < 32) hc[w][f] = fmaxf(ah, 0.0f);

  float logit = pb2[f];
#pragma unroll
  for (int k = 0; k < 32; ++k) logit = fmaf(hc[w][k], pW2[k*64 + f], logit);
  float mx = wredmax(logit);
  float e  = __expf(logit - mx);
  float se = wredsum(e);
  float wt = e / se;
  float v0 = wredsum(m0a + m0b);
  float v1 = wredsum(m1a + m1b);
  float v2 = wredsum(m2a + m2b);
  if (ok){
    float* cvn = XCV + (size_t)n*384 + 192;
    cvn[f] = v0 * wt; cvn[64+f] = v1 * wt; cvn[128+f] = v2 * wt;
  }
}

// ---- K2 v2: gather form. One wave per atom i; register accumulation; no atomics. ----
__global__ __launch_bounds__(256) void k_gather(
    const float* __restrict__ pair, const int* __restrict__ elist,
    const int* __restrict__ start, const int* __restrict__ idx_j,
    const float* __restrict__ fW, const float* __restrict__ fb,
    const float* __restrict__ XCV,
    float* __restrict__ dq, float* __restrict__ dmu, int l, int Ntot)
{
  int w = threadIdx.x >> 6;
  int f = threadIdx.x & 63;
  int i = blockIdx.x * 4 + w;
  if (i >= Ntot) return;
  const int col = l * 192;

  // hoist lane-f filter weights (60) + biases (3) into registers
  float fw0[NRBF], fw1[NRBF], fw2[NRBF];
#pragma unroll
  for (int r = 0; r < NRBF; ++r){
    const float* fr = fW + r*384 + col;
    fw0[r] = fr[f]; fw1[r] = fr[64 + f]; fw2[r] = fr[128 + f];
  }
  float fb0 = fb[col + f], fb1 = fb[col + 64 + f], fb2 = fb[col + 128 + f];

  float dqa = 0.f, dm0 = 0.f, dm1 = 0.f, dm2 = 0.f;
  int e0 = start[i], e1 = start[i+1];
  for (int e = e0; e < e1; ++e){
    int p = elist[e];
    const float4* pr4 = (const float4*)(pair + (size_t)p * 24);
    float4 v0 = pr4[0], v1 = pr4[1], v2 = pr4[2], v3 = pr4[3], v4 = pr4[4], v5 = pr4[5];
    int j = idx_j[p];
    float fc = v0.w;
    float ph[NRBF] = {v1.x,v1.y,v1.z,v1.w, v2.x,v2.y,v2.z,v2.w,
                      v3.x,v3.y,v3.z,v3.w, v4.x,v4.y,v4.z,v4.w,
                      v5.x,v5.y,v5.z,v5.w};
    float w0 = fb0 * fc, w1 = fb1 * fc, w2 = fb2 * fc;
#pragma unroll
    for (int r = 0; r < NRBF; ++r){
      w0 = fmaf(ph[r], fw0[r], w0);
      w1 = fmaf(ph[r], fw1[r], w1);
      w2 = fmaf(ph[r], fw2[r], w2);
    }
    const float* xj = XCV + (size_t)j * 384;
    dqa = fmaf(xj[f], w0, dqa);
    float dmR = xj[64 + f]  * w1;
    float dmm = xj[128 + f] * w2;
    dm0 = fmaf(dmR, v0.x, fmaf(dmm, xj[192 + f], dm0));
    dm1 = fmaf(dmR, v0.y, fmaf(dmm, xj[256 + f], dm1));
    dm2 = fmaf(dmR, v0.z, fmaf(dmm, xj[320 + f], dm2));
  }
  dq[(size_t)i*64 + f] = dqa;
  float* dmn = dmu + (size_t)i*192;
  dmn[f] = dm0; dmn[64 + f] = dm1; dmn[128 + f] = dm2;
}

// ---- K3a: tv only. 8 atoms/block (2 per wave). Weight tiles staged in LDS. ----
__global__ __launch_bounds__(256) void k_tv(
    const float* __restrict__ dmuA, const float* __restrict__ XCV,
    const float* __restrict__ rW1, const float* __restrict__ rb1,
    const float* __restrict__ rW2S, const float* __restrict__ rb2Tl,
    float* __restrict__ MUI, float* __restrict__ TV, int Ntot)
{
  __shared__ float mus[8][3][64];   // 6 KB
  __shared__ float svs[8][64];      // 2 KB
  __shared__ float4 wt4[4096];      // 64 KB
  __shared__ float rbt[8][64];      // 2 KB
  int t = threadIdx.x;
  int w = t >> 6, f = t & 63;
  int base = blockIdx.x * 8;

#pragma unroll
  for (int s = 0; s < 2; ++s){
    int a = w*2 + s;
    int n = base + a; bool ok = (n < Ntot); if (!ok) n = Ntot - 1;
    const float* dmn = dmuA + (size_t)n*192;
    const float* cvn = XCV  + (size_t)n*384 + 192;
    float m0 = dmn[f]       + cvn[f];
    float m1 = dmn[64 + f]  + cvn[64 + f];
    float m2 = dmn[128 + f] + cvn[128 + f];
    mus[a][0][f] = m0; mus[a][1][f] = m1; mus[a][2][f] = m2;
    svs[a][f] = sqrtf(m0*m0 + m1*m1 + m2*m2 + EPSV);
    if (ok){
      float* mo = MUI + (size_t)n*192;
      mo[f] = m0; mo[64+f] = m1; mo[128+f] = m2;
    }
  }
  __syncthreads();

  int ki = f & 31;
  int a_h = w*2 + (f >> 5);
  float ah = rb1[ki];
#pragma unroll
  for (int c = 0; c < 64; ++c) ah = fmaf(svs[a_h][c], rW1[c*32 + ki], ah);
  ah = fmaxf(ah, 0.0f);
  float hreg[2][32];
#pragma unroll
  for (int k = 0; k < 32; ++k){
    hreg[0][k] = __shfl(ah, k, 64);
    hreg[1][k] = __shfl(ah, 32 + k, 64);
  }

  const int a0 = w*2, a1 = a0 + 1;
  float mf00 = mus[a0][0][f], mf01 = mus[a0][1][f], mf02 = mus[a0][2][f];
  float mf10 = mus[a1][0][f], mf11 = mus[a1][1][f], mf12 = mus[a1][2][f];
  float tv00=0,tv01=0,tv02=0, tv10=0,tv11=0,tv12=0;
  const int sw8 = (f & 7);

  for (int ct = 0; ct < 8; ++ct){
    __syncthreads();
    const float4* src = (const float4*)rW2S + (size_t)ct*4096;
#pragma unroll
    for (int i = 0; i < 16; ++i) wt4[t + i*256] = src[t + i*256];
    if (t < 128) ((float4*)rbt)[t] = ((const float4*)(rb2Tl + ct*512))[t];
    __syncthreads();

#pragma unroll
    for (int cc = 0; cc < 8; ++cc){
      int c = ct*8 + cc;
      float u00 = mus[a0][0][c], u01 = mus[a0][1][c], u02 = mus[a0][2][c];
      float u10 = mus[a1][0][c], u11 = mus[a1][1][c], u12 = mus[a1][2][c];
      float g0 = u00*mf00 + u01*mf01 + u02*mf02;
      float g1 = u10*mf10 + u11*mf11 + u12*mf12;
      float acc0 = rbt[cc][f];
      float acc1 = acc0;
      const float4* wrow = &wt4[(cc*64 + f)*8];
#pragma unroll
      for (int kq = 0; kq < 8; ++kq){
        float4 wv = wrow[kq ^ sw8];
        int k0 = kq*4;
        acc0 = fmaf(hreg[0][k0+0], wv.x, acc0);
        acc0 = fmaf(hreg[0][k0+1], wv.y, acc0);
        acc0 = fmaf(hreg[0][k0+2], wv.z, acc0);
        acc0 = fmaf(hreg[0][k0+3], wv.w, acc0);
        acc1 = fmaf(hreg[1][k0+0], wv.x, acc1);
        acc1 = fmaf(hreg[1][k0+1], wv.y, acc1);
        acc1 = fmaf(hreg[1][k0+2], wv.z, acc1);
        acc1 = fmaf(hreg[1][k0+3], wv.w, acc1);
      }
      float mm0 = acc0 * g0, mm1 = acc1 * g1;
      tv00 = fmaf(u00, mm0, tv00); tv01 = fmaf(u01, mm0, tv01); tv02 = fmaf(u02, mm0, tv02);
      tv10 = fmaf(u10, mm1, tv10); tv11 = fmaf(u11, mm1, tv11); tv12 = fmaf(u12, mm1, tv12);
    }
  }

  int n0 = base + a0, n1 = base + a1;
  if (n0 < Ntot){
    float* tvp = TV + (size_t)n0*192;
    tvp[f] = tv00; tvp[64+f] = tv01; tvp[128+f] = tv02;
  }
  if (n1 < Ntot){
    float* tvp = TV + (size_t)n1*192;
    tvp[f] = tv10; tvp[64+f] = tv11; tvp[128+f] = tv12;
  }
}

// ---- K3b: mixing tail. 16 atoms/block (4 per wave), weights LDS-staged. ----
__global__ __launch_bounds__(256) void k_mix2(
    float* __restrict__ q, float* __restrict__ mu,
    const float* __restrict__ dq, const float* __restrict__ MUI, const float* __restrict__ TV,
    const float* __restrict__ mW1, const float* __restrict__ mb1,
    const float* __restrict__ mW2, const float* __restrict__ mb2,
    const float* __restrict__ Wm, int Ntot)
{
  __shared__ float wbuf[12288];     // 48 KB
  __shared__ float mua[16][3][64];  // 12 KB
  __shared__ float ava[16][128];    // 8 KB
  __shared__ float h2a[16][64];     // 4 KB
  int t = threadIdx.x;
  int w = t >> 6, f = t & 63;
  int base = blockIdx.x * 16;
  const int aw = w * 4;
  float4* wt4 = (float4*)wbuf;

  float qv[4], m0[4], m1[4], m2[4];
#pragma unroll
  for (int s = 0; s < 4; ++s){
    int a = aw + s;
    int n = base + a; if (n >= Ntot) n = Ntot - 1;
    qv[s] = q[(size_t)n*64 + f] + dq[(size_t)n*64 + f];
    const float* mi = MUI + (size_t)n*192;
    m0[s] = mi[f]; m1[s] = mi[64 + f]; m2[s] = mi[128 + f];
    mua[a][0][f] = m0[s]; mua[a][1][f] = m1[s]; mua[a][2][f] = m2[s];
  }

#pragma unroll
  for (int i = 0; i < 8; ++i) wt4[t + i*256] = ((const float4*)Wm)[t + i*256];
  __syncthreads();

  float V0[4]={0,0,0,0}, V1[4]={0,0,0,0}, V2[4]={0,0,0,0};
  float W0[4]={0,0,0,0}, W1[4]={0,0,0,0}, W2[4]={0,0,0,0};
  for (int k = 0; k < 64; ++k){
    float wv = wbuf[k*128 + f];
    float ww = wbuf[k*128 + 64 + f];
#pragma unroll
    for (int s = 0; s < 4; ++s){
      int a = aw + s;
      float b0 = mua[a][0][k], b1 = mua[a][1][k], b2 = mua[a][2][k];
      V0[s] = fmaf(b0, wv, V0[s]); V1[s] = fmaf(b1, wv, V1[s]); V2[s] = fmaf(b2, wv, V2[s]);
      W0[s] = fmaf(b0, ww, W0[s]); W1[s] = fmaf(b1, ww, W1[s]); W2[s] = fmaf(b2, ww, W2[s]);
    }
  }
  float dot[4];
#pragma unroll
  for (int s = 0; s < 4; ++s){
    int a = aw + s;
    ava[a][f] = qv[s];
    ava[a][64 + f] = sqrtf(V0[s]*V0[s] + V1[s]*V1[s] + V2[s]*V2[s] + EPSV);
    dot[s] = V0[s]*W0[s] + V1[s]*W1[s] + V2[s]*W2[s];
  }

  __syncthreads();
#pragma unroll
  for (int i = 0; i < 8; ++i) wt4[t + i*256] = ((const float4*)mW1)[t + i*256];
  __syncthreads();

  float acc[4];
#pragma unroll
  for (int s = 0; s < 4; ++s) acc[s] = mb1[f];
  for (int k = 0; k < 128; ++k){
    float wv = wbuf[k*64 + f];
#pragma unroll
    for (int s = 0; s < 4; ++s) acc[s] = fmaf(ava[aw + s][k], wv, acc[s]);
  }
#pragma unroll
  for (int s = 0; s < 4; ++s) h2a[aw + s][f] = silu_f(acc[s]);

  __syncthreads();
#pragma unroll
  for (int i = 0; i < 12; ++i) wt4[t + i*256] = ((const float4*)mW2)[t + i*256];
  __syncthreads();

  float y0[4], y1[4], y2[4];
#pragma unroll
  for (int s = 0; s < 4; ++s){ y0[s] = mb2[f]; y1[s] = mb2[64+f]; y2[s] = mb2[128+f]; }
  for (int k = 0; k < 64; ++k){
    float u0 = wbuf[k*192 + f];
    float u1 = wbuf[k*192 + 64 + f];
    float u2 = wbuf[k*192 + 128 + f];
#pragma unroll
    for (int s = 0; s < 4; ++s){
      float h = h2a[aw + s][k];
      y0[s] = fmaf(h, u0, y0[s]); y1[s] = fmaf(h, u1, y1[s]); y2[s] = fmaf(h, u2, y2[s]);
    }
  }

#pragma unroll
  for (int s = 0; s < 4; ++s){
    int n = base + aw + s;
    if (n < Ntot){
      q[(size_t)n*64 + f] = qv[s] + y0[s] + y2[s]*dot[s];
      const float* tvp = TV + (size_t)n*192;
      float* mun = mu + (size_t)n*384;
      mun[0*128 + f] = fmaf(y1[s], W0[s], m0[s]); mun[0*128 + 64 + f] = tvp[f];
      mun[1*128 + f] = fmaf(y1[s], W1[s], m1[s]); mun[1*128 + 64 + f] = tvp[64+f];
      mun[2*128 + f] = fmaf(y1[s], W2[s], m2[s]); mun[2*128 + 64 + f] = tvp[128+f];
    }
  }
}

extern "C" void kernel_launch(void* const* d_in, const int* in_sizes, int n_in,
                              void* d_out, int out_size, void* d_ws, size_t ws_size,
                              hipStream_t stream)
{
  const int*   Z      = (const int*)  d_in[0];
  const float* Rij    = (const float*)d_in[1];
  const int*   idx_i  = (const int*)  d_in[2];
  const int*   idx_j  = (const int*)  d_in[3];
  const float* embed  = (const float*)d_in[5];
  const float* fW     = (const float*)d_in[6];
  const float* fb     = (const float*)d_in[7];
  const float* ctxW1  = (const float*)d_in[8];
  const float* ctxb1  = (const float*)d_in[9];
  const float* ctxW2  = (const float*)d_in[10];
  const float* ctxb2  = (const float*)d_in[11];
  const float* compW1 = (const float*)d_in[12];
  const float* compb1 = (const float*)d_in[13];
  const float* compW2 = (const float*)d_in[14];
  const float* compb2 = (const float*)d_in[15];
  const float* recW1  = (const float*)d_in[16];
  const float* recb1  = (const float*)d_in[17];
  const float* recW2  = (const float*)d_in[18];
  const float* recb2  = (const float*)d_in[19];
  const float* mixW1  = (const float*)d_in[20];
  const float* mixb1  = (const float*)d_in[21];
  const float* mixW2  = (const float*)d_in[22];
  const float* mixb2  = (const float*)d_in[23];
  const float* muMixW = (const float*)d_in[24];

  const int N = in_sizes[0];
  const int P = in_sizes[1] / 3;

  float* ws    = (float*)d_ws;
  float* pair  = ws;                         // P*24
  float* q     = pair  + (size_t)P*24;       // N*64
  float* mu    = q     + (size_t)N*64;       // N*384
  float* XCV   = mu    + (size_t)N*384;      // N*384
  float* dq    = XCV   + (size_t)N*384;      // N*64
  float* dmu   = dq    + (size_t)N*64;       // N*192
  float* rW2S  = dmu   + (size_t)N*192;      // 262144
  float* rb2T  = rW2S  + (size_t)262144;     // 8192
  float* TV    = rb2T  + (size_t)8192;       // N*192
  float* MUI   = TV    + (size_t)N*192;      // N*192
  int*   cnt    = (int*)(MUI + (size_t)N*192); // N
  int*   startA = cnt    + N;                  // N+1
  int*   cursor = startA + (N + 1);            // N
  int*   elist  = cursor + N;                  // P

  k_pairprep<<<(P + 255)/256, 256, 0, stream>>>(Rij, pair, P);
  k_transpose_w<<<(262144 + 255)/256, 256, 0, stream>>>(recW2, recb2, rW2S, rb2T);
  hipMemsetAsync(mu, 0, (size_t)N*384*sizeof(float), stream);
  hipMemsetAsync(cnt, 0, (size_t)N*sizeof(int), stream);
  k_init_q<<<(N*FD + 255)/256, 256, 0, stream>>>(Z, embed, q, N);

  // CSR build (idx_i fixed across layers)
  k_count<<<(P + 255)/256, 256, 0, stream>>>(idx_i, cnt, P);
  k_scan<<<1, 1024, 0, stream>>>(cnt, startA, cursor, N);
  k_scatter<<<(P + 255)/256, 256, 0, stream>>>(idx_i, cursor, elist, P);

  const int ablk4  = (N + 3) / 4;
  const int ablk8  = (N + 7) / 8;
  const int ablk16 = (N + 15) / 16;
  for (int l = 0; l < 2; ++l){
    k_atom_pre<<<ablk4, 256, 0, stream>>>(q, mu,
        ctxW1 + (size_t)l*64*64,  ctxb1 + (size_t)l*64,
        ctxW2 + (size_t)l*64*192, ctxb2 + (size_t)l*192,
        compW1 + (size_t)l*128*32, compb1 + (size_t)l*32,
        compW2 + (size_t)l*32*64,  compb2 + (size_t)l*64,
        XCV, N);
    k_gather<<<ablk4, 256, 0, stream>>>(pair, elist, startA, idx_j, fW, fb, XCV,
        dq, dmu, l, N);
    k_tv<<<ablk8, 256, 0, stream>>>(dmu, XCV,
        recW1 + (size_t)l*64*32, recb1 + (size_t)l*32,
        rW2S + (size_t)l*131072, rb2T + (size_t)l*4096,
        MUI, TV, N);
    k_mix2<<<ablk16, 256, 0, stream>>>(q, mu, dq, MUI, TV,
        mixW1 + (size_t)l*128*64, mixb1 + (size_t)l*64,
        mixW2 + (size_t)l*64*192, mixb2 + (size_t)l*192,
        muMixW + (size_t)l*64*128, N);
  }

  hipMemcpyAsync(d_out, q, (size_t)N*64*sizeof(float), hipMemcpyDeviceToDevice, stream);
  hipMemcpyAsync((float*)d_out + (size_t)N*64, mu, (size_t)N*384*sizeof(float),
                 hipMemcpyDeviceToDevice, stream);
}

// Round 7
// 741.441 us; speedup vs baseline: 2.5627x; 1.0370x over previous
//
#include <hip/hip_runtime.h>
#include <math.h>

#define FD 64
#define NRBF 20
#define CUT 5.0f
#define EPSV 1e-8f
#define PI_F 3.14159265358979f

__device__ __forceinline__ float wredsum(float v){
#pragma unroll
  for (int m = 32; m >= 1; m >>= 1) v += __shfl_xor(v, m, 64);
  return v;
}
__device__ __forceinline__ float wredmax(float v){
#pragma unroll
  for (int m = 32; m >= 1; m >>= 1) v = fmaxf(v, __shfl_xor(v, m, 64));
  return v;
}
__device__ __forceinline__ float silu_f(float x){ return x * (1.0f / (1.0f + __expf(-x))); }

// ---- K0: per-pair precompute: dir(3), fcut(1), phi*fcut(20) -> 24 floats ----
__global__ __launch_bounds__(256) void k_pairprep(const float* __restrict__ Rij,
                                                  float* __restrict__ pair, int P)
{
  int p = blockIdx.x * blockDim.x + threadIdx.x;
  if (p >= P) return;
  float rx = Rij[3*p+0], ry = Rij[3*p+1], rz = Rij[3*p+2];
  float d = sqrtf(rx*rx + ry*ry + rz*rz);
  float inv = 1.0f / d;
  float fc = (d < CUT) ? 0.5f * (__cosf(PI_F * d / CUT) + 1.0f) : 0.0f;
  float* pr = pair + (size_t)p * 24;
  pr[0] = rx*inv; pr[1] = ry*inv; pr[2] = rz*inv; pr[3] = fc;
  const float width = CUT / (float)(NRBF - 1);
#pragma unroll
  for (int r = 0; r < NRBF; ++r){
    float t = (d - width * (float)r) / width;
    pr[4+r] = __expf(-0.5f * t * t) * fc;
  }
}

// ---- CSR build: histogram, scan, scatter ----
__global__ __launch_bounds__(256) void k_count(const int* __restrict__ idx_i,
                                               int* __restrict__ cnt, int P)
{
  int p = blockIdx.x * blockDim.x + threadIdx.x;
  if (p < P) atomicAdd(&cnt[idx_i[p]], 1);
}

__global__ __launch_bounds__(1024) void k_scan(const int* __restrict__ cnt,
                                               int* __restrict__ start,
                                               int* __restrict__ cursor, int N)
{
  __shared__ int part[1024];
  int t = threadIdx.x;
  int chunk = (N + 1023) / 1024;
  int lo = t * chunk, hi = lo + chunk; if (hi > N) hi = N;
  int s = 0;
  for (int i = lo; i < hi; ++i) s += cnt[i];
  part[t] = s;
  __syncthreads();
  for (int off = 1; off < 1024; off <<= 1){
    int v = 0;
    if (t >= off) v = part[t - off];
    __syncthreads();
    if (t >= off) part[t] += v;
    __syncthreads();
  }
  int run = (t == 0) ? 0 : part[t-1];
  for (int i = lo; i < hi; ++i){ start[i] = run; cursor[i] = run; run += cnt[i]; }
  if (t == 1023) start[N] = run;
}

__global__ __launch_bounds__(256) void k_scatter(const int* __restrict__ idx_i,
                                                 int* __restrict__ cursor,
                                                 int* __restrict__ elist, int P)
{
  int p = blockIdx.x * blockDim.x + threadIdx.x;
  if (p < P){
    int pos = atomicAdd(&cursor[idx_i[p]], 1);
    elist[pos] = p;
  }
}

// ---- transpose+swizzle rec_W2 -> rW2S[l][c][f][kq^(f&7)][km], rb2 -> rb2T[l][c][f] ----
__global__ __launch_bounds__(256) void k_transpose_w(const float* __restrict__ rW2,
                                                     const float* __restrict__ rb2,
                                                     float* __restrict__ rW2S,
                                                     float* __restrict__ rb2T)
{
  int t = blockIdx.x * blockDim.x + threadIdx.x;
  if (t < 2*64*32*64){
    int km = t & 3;
    int kq = (t >> 2) & 7;
    int f  = (t >> 5) & 63;
    int c  = (t >> 11) & 63;
    int l  = t >> 17;
    int k  = ((kq ^ (f & 7)) << 2) | km;
    rW2S[t] = rW2[((size_t)(l*32 + k))*4096 + f*64 + c];
  }
  if (t < 2*64*64){
    int f = t & 63, c = (t >> 6) & 63, l = t >> 12;
    rb2T[t] = rb2[(size_t)l*4096 + f*64 + c];
  }
}

// ---- K_init: q = embed[Z] ----
__global__ __launch_bounds__(256) void k_init_q(const int* __restrict__ Z,
                                                const float* __restrict__ embed,
                                                float* __restrict__ q, int Ntot)
{
  int t = blockIdx.x * blockDim.x + threadIdx.x;
  if (t >= Ntot * FD) return;
  int n = t >> 6, f = t & 63;
  q[t] = embed[Z[n]*FD + f];
}

// ---- K1: per-atom: XCV[n][0..191] = X, XCV[n][192..383] = compress(mu) ----
__global__ __launch_bounds__(256) void k_atom_pre(
    const float* __restrict__ q, const float* __restrict__ mu,
    const float* __restrict__ cW1, const float* __restrict__ cb1,
    const float* __restrict__ cW2, const float* __restrict__ cb2,
    const float* __restrict__ pW1, const float* __restrict__ pb1,
    const float* __restrict__ pW2, const float* __restrict__ pb2,
    float* __restrict__ XCV, int Ntot)
{
  __shared__ float qs[4][64];
  __shared__ float h1[4][64];
  __shared__ float sbuf[4][128];
  __shared__ float hc[4][32];
  int w = threadIdx.x >> 6;
  int f = threadIdx.x & 63;
  int n = blockIdx.x * 4 + w;
  bool ok = (n < Ntot);
  if (!ok) n = Ntot - 1;

  float qv = q[(size_t)n*64 + f];
  qs[w][f] = qv;

  const float* mun = mu + (size_t)n * 384;
  float m0a = mun[0*128 + f],      m1a = mun[1*128 + f],      m2a = mun[2*128 + f];
  float m0b = mun[0*128 + 64 + f], m1b = mun[1*128 + 64 + f], m2b = mun[2*128 + 64 + f];
  sbuf[w][f]      = sqrtf(m0a*m0a + m1a*m1a + m2a*m2a + EPSV);
  sbuf[w][64 + f] = sqrtf(m0b*m0b + m1b*m1b + m2b*m2b + EPSV);

  float acc = cb1[f];
#pragma unroll
  for (int k = 0; k < 64; ++k) acc = fmaf(qs[w][k], cW1[k*64 + f], acc);
  h1[w][f] = silu_f(acc);

  float x0 = cb2[f], x1 = cb2[64+f], x2 = cb2[128+f];
#pragma unroll
  for (int k = 0; k < 64; ++k){
    float h = h1[w][k];
    x0 = fmaf(h, cW2[k*192 + f],       x0);
    x1 = fmaf(h, cW2[k*192 + 64 + f],  x1);
    x2 = fmaf(h, cW2[k*192 + 128 + f], x2);
  }
  if (ok){
    float* Xn = XCV + (size_t)n*384;
    Xn[f] = x0; Xn[64+f] = x1; Xn[128+f] = x2;
  }

  int ki = f & 31;
  float ah = pb1[ki];
#pragma unroll
  for (int c = 0; c < 128; ++c) ah = fmaf(sbuf[w][c], pW1[c*32 + ki], ah);
  if (f < 32) hc[w][f] = fmaxf(ah, 0.0f);

  float logit = pb2[f];
#pragma unroll
  for (int k = 0; k < 32; ++k) logit = fmaf(hc[w][k], pW2[k*64 + f], logit);
  float mx = wredmax(logit);
  float e  = __expf(logit - mx);
  float se = wredsum(e);
  float wt = e / se;
  float v0 = wredsum(m0a + m0b);
  float v1 = wredsum(m1a + m1b);
  float v2 = wredsum(m2a + m2b);
  if (ok){
    float* cvn = XCV + (size_t)n*384 + 192;
    cvn[f] = v0 * wt; cvn[64+f] = v1 * wt; cvn[128+f] = v2 * wt;
  }
}

// ---- K2 v3: gather form, unroll-2 for MLP. One wave per atom i; no atomics. ----
__global__ __launch_bounds__(256) void k_gather(
    const float* __restrict__ pair, const int* __restrict__ elist,
    const int* __restrict__ start, const int* __restrict__ idx_j,
    const float* __restrict__ fW, const float* __restrict__ fb,
    const float* __restrict__ XCV,
    float* __restrict__ dq, float* __restrict__ dmu, int l, int Ntot)
{
  int w = threadIdx.x >> 6;
  int f = threadIdx.x & 63;
  int i = blockIdx.x * 4 + w;
  if (i >= Ntot) return;
  const int col = l * 192;

  float fw0[NRBF], fw1[NRBF], fw2[NRBF];
#pragma unroll
  for (int r = 0; r < NRBF; ++r){
    const float* fr = fW + r*384 + col;
    fw0[r] = fr[f]; fw1[r] = fr[64 + f]; fw2[r] = fr[128 + f];
  }
  float fb0 = fb[col + f], fb1 = fb[col + 64 + f], fb2 = fb[col + 128 + f];

  float dqa = 0.f, dm0 = 0.f, dm1 = 0.f, dm2 = 0.f;
  int e0 = start[i], e1 = start[i+1];
  int e = e0;
  for (; e + 2 <= e1; e += 2){
    int pA = elist[e], pB = elist[e+1];
    int jA = idx_j[pA], jB = idx_j[pB];
    const float4* prA = (const float4*)(pair + (size_t)pA * 24);
    const float4* prB = (const float4*)(pair + (size_t)pB * 24);
    float4 A0=prA[0],A1=prA[1],A2=prA[2],A3=prA[3],A4=prA[4],A5=prA[5];
    float4 B0=prB[0],B1=prB[1],B2=prB[2],B3=prB[3],B4=prB[4],B5=prB[5];
    const float* xA = XCV + (size_t)jA * 384;
    const float* xB = XCV + (size_t)jB * 384;
    float xA0=xA[f], xA1=xA[64+f], xA2=xA[128+f], cA0=xA[192+f], cA1=xA[256+f], cA2=xA[320+f];
    float xB0=xB[f], xB1=xB[64+f], xB2=xB[128+f], cB0=xB[192+f], cB1=xB[256+f], cB2=xB[320+f];
    float phA[NRBF] = {A1.x,A1.y,A1.z,A1.w, A2.x,A2.y,A2.z,A2.w,
                       A3.x,A3.y,A3.z,A3.w, A4.x,A4.y,A4.z,A4.w,
                       A5.x,A5.y,A5.z,A5.w};
    float phB[NRBF] = {B1.x,B1.y,B1.z,B1.w, B2.x,B2.y,B2.z,B2.w,
                       B3.x,B3.y,B3.z,B3.w, B4.x,B4.y,B4.z,B4.w,
                       B5.x,B5.y,B5.z,B5.w};
    float wA0=fb0*A0.w, wA1=fb1*A0.w, wA2=fb2*A0.w;
    float wB0=fb0*B0.w, wB1=fb1*B0.w, wB2=fb2*B0.w;
#pragma unroll
    for (int r = 0; r < NRBF; ++r){
      wA0 = fmaf(phA[r], fw0[r], wA0);
      wA1 = fmaf(phA[r], fw1[r], wA1);
      wA2 = fmaf(phA[r], fw2[r], wA2);
      wB0 = fmaf(phB[r], fw0[r], wB0);
      wB1 = fmaf(phB[r], fw1[r], wB1);
      wB2 = fmaf(phB[r], fw2[r], wB2);
    }
    dqa = fmaf(xA0, wA0, dqa);
    float dmRA = xA1 * wA1, dmmA = xA2 * wA2;
    dm0 = fmaf(dmRA, A0.x, fmaf(dmmA, cA0, dm0));
    dm1 = fmaf(dmRA, A0.y, fmaf(dmmA, cA1, dm1));
    dm2 = fmaf(dmRA, A0.z, fmaf(dmmA, cA2, dm2));
    dqa = fmaf(xB0, wB0, dqa);
    float dmRB = xB1 * wB1, dmmB = xB2 * wB2;
    dm0 = fmaf(dmRB, B0.x, fmaf(dmmB, cB0, dm0));
    dm1 = fmaf(dmRB, B0.y, fmaf(dmmB, cB1, dm1));
    dm2 = fmaf(dmRB, B0.z, fmaf(dmmB, cB2, dm2));
  }
  if (e < e1){
    int p = elist[e];
    int j = idx_j[p];
    const float4* pr4 = (const float4*)(pair + (size_t)p * 24);
    float4 v0 = pr4[0], v1 = pr4[1], v2 = pr4[2], v3 = pr4[3], v4 = pr4[4], v5 = pr4[5];
    const float* xj = XCV + (size_t)j * 384;
    float ph[NRBF] = {v1.x,v1.y,v1.z,v1.w, v2.x,v2.y,v2.z,v2.w,
                      v3.x,v3.y,v3.z,v3.w, v4.x,v4.y,v4.z,v4.w,
                      v5.x,v5.y,v5.z,v5.w};
    float w0 = fb0 * v0.w, w1 = fb1 * v0.w, w2 = fb2 * v0.w;
#pragma unroll
    for (int r = 0; r < NRBF; ++r){
      w0 = fmaf(ph[r], fw0[r], w0);
      w1 = fmaf(ph[r], fw1[r], w1);
      w2 = fmaf(ph[r], fw2[r], w2);
    }
    dqa = fmaf(xj[f], w0, dqa);
    float dmR = xj[64 + f]  * w1;
    float dmm = xj[128 + f] * w2;
    dm0 = fmaf(dmR, v0.x, fmaf(dmm, xj[192 + f], dm0));
    dm1 = fmaf(dmR, v0.y, fmaf(dmm, xj[256 + f], dm1));
    dm2 = fmaf(dmR, v0.z, fmaf(dmm, xj[320 + f], dm2));
  }
  dq[(size_t)i*64 + f] = dqa;
  float* dmn = dmu + (size_t)i*192;
  dmn[f] = dm0; dmn[64 + f] = dm1; dmn[128 + f] = dm2;
}

// ---- K3a v3: tv. 512 threads, 16 atoms/block (2 per wave), 4-c 32KB tiles. ----
__global__ __launch_bounds__(512) void k_tv(
    const float* __restrict__ dmuA, const float* __restrict__ XCV,
    const float* __restrict__ rW1, const float* __restrict__ rb1,
    const float* __restrict__ rW2S, const float* __restrict__ rb2Tl,
    float* __restrict__ MUI, float* __restrict__ TV, int Ntot)
{
  __shared__ float mus[16][3][64];  // 12 KB
  __shared__ float svs[16][64];     // 4 KB
  __shared__ float4 wt4[2048];      // 32 KB: 4 c x 64 f x 8 kq-quad
  __shared__ float rbt[4][64];      // 1 KB
  int t = threadIdx.x;
  int w = t >> 6, f = t & 63;
  int base = blockIdx.x * 16;

#pragma unroll
  for (int s = 0; s < 2; ++s){
    int a = w*2 + s;
    int n = base + a; bool ok = (n < Ntot); if (!ok) n = Ntot - 1;
    const float* dmn = dmuA + (size_t)n*192;
    const float* cvn = XCV  + (size_t)n*384 + 192;
    float m0 = dmn[f]       + cvn[f];
    float m1 = dmn[64 + f]  + cvn[64 + f];
    float m2 = dmn[128 + f] + cvn[128 + f];
    mus[a][0][f] = m0; mus[a][1][f] = m1; mus[a][2][f] = m2;
    svs[a][f] = sqrtf(m0*m0 + m1*m1 + m2*m2 + EPSV);
    if (ok){
      float* mo = MUI + (size_t)n*192;
      mo[f] = m0; mo[64+f] = m1; mo[128+f] = m2;
    }
  }
  __syncthreads();

  int ki = f & 31;
  int a_h = w*2 + (f >> 5);
  float ah = rb1[ki];
#pragma unroll
  for (int c = 0; c < 64; ++c) ah = fmaf(svs[a_h][c], rW1[c*32 + ki], ah);
  ah = fmaxf(ah, 0.0f);
  float hreg[2][32];
#pragma unroll
  for (int k = 0; k < 32; ++k){
    hreg[0][k] = __shfl(ah, k, 64);
    hreg[1][k] = __shfl(ah, 32 + k, 64);
  }

  const int a0 = w*2, a1 = a0 + 1;
  float mf00 = mus[a0][0][f], mf01 = mus[a0][1][f], mf02 = mus[a0][2][f];
  float mf10 = mus[a1][0][f], mf11 = mus[a1][1][f], mf12 = mus[a1][2][f];
  float tv00=0,tv01=0,tv02=0, tv10=0,tv11=0,tv12=0;
  const int sw8 = (f & 7);

  for (int ct = 0; ct < 16; ++ct){
    __syncthreads();
    const float4* src = (const float4*)rW2S + (size_t)ct*2048;
#pragma unroll
    for (int i = 0; i < 4; ++i) wt4[t + i*512] = src[t + i*512];
    if (t < 64) ((float4*)rbt)[t] = ((const float4*)(rb2Tl + ct*256))[t];
    __syncthreads();

#pragma unroll
    for (int cc = 0; cc < 4; ++cc){
      int c = ct*4 + cc;
      float u00 = mus[a0][0][c], u01 = mus[a0][1][c], u02 = mus[a0][2][c];
      float u10 = mus[a1][0][c], u11 = mus[a1][1][c], u12 = mus[a1][2][c];
      float g0 = u00*mf00 + u01*mf01 + u02*mf02;
      float g1 = u10*mf10 + u11*mf11 + u12*mf12;
      float acc0 = rbt[cc][f];
      float acc1 = acc0;
      const float4* wrow = &wt4[(cc*64 + f)*8];
#pragma unroll
      for (int kq = 0; kq < 8; ++kq){
        float4 wv = wrow[kq ^ sw8];
        int k0 = kq*4;
        acc0 = fmaf(hreg[0][k0+0], wv.x, acc0);
        acc0 = fmaf(hreg[0][k0+1], wv.y, acc0);
        acc0 = fmaf(hreg[0][k0+2], wv.z, acc0);
        acc0 = fmaf(hreg[0][k0+3], wv.w, acc0);
        acc1 = fmaf(hreg[1][k0+0], wv.x, acc1);
        acc1 = fmaf(hreg[1][k0+1], wv.y, acc1);
        acc1 = fmaf(hreg[1][k0+2], wv.z, acc1);
        acc1 = fmaf(hreg[1][k0+3], wv.w, acc1);
      }
      float mm0 = acc0 * g0, mm1 = acc1 * g1;
      tv00 = fmaf(u00, mm0, tv00); tv01 = fmaf(u01, mm0, tv01); tv02 = fmaf(u02, mm0, tv02);
      tv10 = fmaf(u10, mm1, tv10); tv11 = fmaf(u11, mm1, tv11); tv12 = fmaf(u12, mm1, tv12);
    }
  }

  int n0 = base + a0, n1 = base + a1;
  if (n0 < Ntot){
    float* tvp = TV + (size_t)n0*192;
    tvp[f] = tv00; tvp[64+f] = tv01; tvp[128+f] = tv02;
  }
  if (n1 < Ntot){
    float* tvp = TV + (size_t)n1*192;
    tvp[f] = tv10; tvp[64+f] = tv11; tvp[128+f] = tv12;
  }
}

// ---- K3b: mixing tail. 16 atoms/block (4 per wave), weights LDS-staged. ----
__global__ __launch_bounds__(256) void k_mix2(
    float* __restrict__ q, float* __restrict__ mu,
    const float* __restrict__ dq, const float* __restrict__ MUI, const float* __restrict__ TV,
    const float* __restrict__ mW1, const float* __restrict__ mb1,
    const float* __restrict__ mW2, const float* __restrict__ mb2,
    const float* __restrict__ Wm, int Ntot)
{
  __shared__ float wbuf[12288];     // 48 KB
  __shared__ float mua[16][3][64];  // 12 KB
  __shared__ float ava[16][128];    // 8 KB
  __shared__ float h2a[16][64];     // 4 KB
  int t = threadIdx.x;
  int w = t >> 6, f = t & 63;
  int base = blockIdx.x * 16;
  const int aw = w * 4;
  float4* wt4 = (float4*)wbuf;

  float qv[4], m0[4], m1[4], m2[4];
#pragma unroll
  for (int s = 0; s < 4; ++s){
    int a = aw + s;
    int n = base + a; if (n >= Ntot) n = Ntot - 1;
    qv[s] = q[(size_t)n*64 + f] + dq[(size_t)n*64 + f];
    const float* mi = MUI + (size_t)n*192;
    m0[s] = mi[f]; m1[s] = mi[64 + f]; m2[s] = mi[128 + f];
    mua[a][0][f] = m0[s]; mua[a][1][f] = m1[s]; mua[a][2][f] = m2[s];
  }

#pragma unroll
  for (int i = 0; i < 8; ++i) wt4[t + i*256] = ((const float4*)Wm)[t + i*256];
  __syncthreads();

  float V0[4]={0,0,0,0}, V1[4]={0,0,0,0}, V2[4]={0,0,0,0};
  float W0[4]={0,0,0,0}, W1[4]={0,0,0,0}, W2[4]={0,0,0,0};
  for (int k = 0; k < 64; ++k){
    float wv = wbuf[k*128 + f];
    float ww = wbuf[k*128 + 64 + f];
#pragma unroll
    for (int s = 0; s < 4; ++s){
      int a = aw + s;
      float b0 = mua[a][0][k], b1 = mua[a][1][k], b2 = mua[a][2][k];
      V0[s] = fmaf(b0, wv, V0[s]); V1[s] = fmaf(b1, wv, V1[s]); V2[s] = fmaf(b2, wv, V2[s]);
      W0[s] = fmaf(b0, ww, W0[s]); W1[s] = fmaf(b1, ww, W1[s]); W2[s] = fmaf(b2, ww, W2[s]);
    }
  }
  float dot[4];
#pragma unroll
  for (int s = 0; s < 4; ++s){
    int a = aw + s;
    ava[a][f] = qv[s];
    ava[a][64 + f] = sqrtf(V0[s]*V0[s] + V1[s]*V1[s] + V2[s]*V2[s] + EPSV);
    dot[s] = V0[s]*W0[s] + V1[s]*W1[s] + V2[s]*W2[s];
  }

  __syncthreads();
#pragma unroll
  for (int i = 0; i < 8; ++i) wt4[t + i*256] = ((const float4*)mW1)[t + i*256];
  __syncthreads();

  float acc[4];
#pragma unroll
  for (int s = 0; s < 4; ++s) acc[s] = mb1[f];
  for (int k = 0; k < 128; ++k){
    float wv = wbuf[k*64 + f];
#pragma unroll
    for (int s = 0; s < 4; ++s) acc[s] = fmaf(ava[aw + s][k], wv, acc[s]);
  }
#pragma unroll
  for (int s = 0; s < 4; ++s) h2a[aw + s][f] = silu_f(acc[s]);

  __syncthreads();
#pragma unroll
  for (int i = 0; i < 12; ++i) wt4[t + i*256] = ((const float4*)mW2)[t + i*256];
  __syncthreads();

  float y0[4], y1[4], y2[4];
#pragma unroll
  for (int s = 0; s < 4; ++s){ y0[s] = mb2[f]; y1[s] = mb2[64+f]; y2[s] = mb2[128+f]; }
  for (int k = 0; k < 64; ++k){
    float u0 = wbuf[k*192 + f];
    float u1 = wbuf[k*192 + 64 + f];
    float u2 = wbuf[k*192 + 128 + f];
#pragma unroll
    for (int s = 0; s < 4; ++s){
      float h = h2a[aw + s][k];
      y0[s] = fmaf(h, u0, y0[s]); y1[s] = fmaf(h, u1, y1[s]); y2[s] = fmaf(h, u2, y2[s]);
    }
  }

#pragma unroll
  for (int s = 0; s < 4; ++s){
    int n = base + aw + s;
    if (n < Ntot){
      q[(size_t)n*64 + f] = qv[s] + y0[s] + y2[s]*dot[s];
      const float* tvp = TV + (size_t)n*192;
      float* mun = mu + (size_t)n*384;
      mun[0*128 + f] = fmaf(y1[s], W0[s], m0[s]); mun[0*128 + 64 + f] = tvp[f];
      mun[1*128 + f] = fmaf(y1[s], W1[s], m1[s]); mun[1*128 + 64 + f] = tvp[64+f];
      mun[2*128 + f] = fmaf(y1[s], W2[s], m2[s]); mun[2*128 + 64 + f] = tvp[128+f];
    }
  }
}

extern "C" void kernel_launch(void* const* d_in, const int* in_sizes, int n_in,
                              void* d_out, int out_size, void* d_ws, size_t ws_size,
                              hipStream_t stream)
{
  const int*   Z      = (const int*)  d_in[0];
  const float* Rij    = (const float*)d_in[1];
  const int*   idx_i  = (const int*)  d_in[2];
  const int*   idx_j  = (const int*)  d_in[3];
  const float* embed  = (const float*)d_in[5];
  const float* fW     = (const float*)d_in[6];
  const float* fb     = (const float*)d_in[7];
  const float* ctxW1  = (const float*)d_in[8];
  const float* ctxb1  = (const float*)d_in[9];
  const float* ctxW2  = (const float*)d_in[10];
  const float* ctxb2  = (const float*)d_in[11];
  const float* compW1 = (const float*)d_in[12];
  const float* compb1 = (const float*)d_in[13];
  const float* compW2 = (const float*)d_in[14];
  const float* compb2 = (const float*)d_in[15];
  const float* recW1  = (const float*)d_in[16];
  const float* recb1  = (const float*)d_in[17];
  const float* recW2  = (const float*)d_in[18];
  const float* recb2  = (const float*)d_in[19];
  const float* mixW1  = (const float*)d_in[20];
  const float* mixb1  = (const float*)d_in[21];
  const float* mixW2  = (const float*)d_in[22];
  const float* mixb2  = (const float*)d_in[23];
  const float* muMixW = (const float*)d_in[24];

  const int N = in_sizes[0];
  const int P = in_sizes[1] / 3;

  float* ws    = (float*)d_ws;
  float* pair  = ws;                         // P*24
  float* q     = pair  + (size_t)P*24;       // N*64
  float* mu    = q     + (size_t)N*64;       // N*384
  float* XCV   = mu    + (size_t)N*384;      // N*384
  float* dq    = XCV   + (size_t)N*384;      // N*64
  float* dmu   = dq    + (size_t)N*64;       // N*192
  float* rW2S  = dmu   + (size_t)N*192;      // 262144
  float* rb2T  = rW2S  + (size_t)262144;     // 8192
  float* TV    = rb2T  + (size_t)8192;       // N*192
  float* MUI   = TV    + (size_t)N*192;      // N*192
  int*   cnt    = (int*)(MUI + (size_t)N*192); // N
  int*   startA = cnt    + N;                  // N+1
  int*   cursor = startA + (N + 1);            // N
  int*   elist  = cursor + N;                  // P

  k_pairprep<<<(P + 255)/256, 256, 0, stream>>>(Rij, pair, P);
  k_transpose_w<<<(262144 + 255)/256, 256, 0, stream>>>(recW2, recb2, rW2S, rb2T);
  hipMemsetAsync(mu, 0, (size_t)N*384*sizeof(float), stream);
  hipMemsetAsync(cnt, 0, (size_t)N*sizeof(int), stream);
  k_init_q<<<(N*FD + 255)/256, 256, 0, stream>>>(Z, embed, q, N);

  // CSR build (idx_i fixed across layers)
  k_count<<<(P + 255)/256, 256, 0, stream>>>(idx_i, cnt, P);
  k_scan<<<1, 1024, 0, stream>>>(cnt, startA, cursor, N);
  k_scatter<<<(P + 255)/256, 256, 0, stream>>>(idx_i, cursor, elist, P);

  const int ablk4  = (N + 3) / 4;
  const int ablk16 = (N + 15) / 16;
  for (int l = 0; l < 2; ++l){
    k_atom_pre<<<ablk4, 256, 0, stream>>>(q, mu,
        ctxW1 + (size_t)l*64*64,  ctxb1 + (size_t)l*64,
        ctxW2 + (size_t)l*64*192, ctxb2 + (size_t)l*192,
        compW1 + (size_t)l*128*32, compb1 + (size_t)l*32,
        compW2 + (size_t)l*32*64,  compb2 + (size_t)l*64,
        XCV, N);
    k_gather<<<ablk4, 256, 0, stream>>>(pair, elist, startA, idx_j, fW, fb, XCV,
        dq, dmu, l, N);
    k_tv<<<ablk16, 512, 0, stream>>>(dmu, XCV,
        recW1 + (size_t)l*64*32, recb1 + (size_t)l*32,
        rW2S + (size_t)l*131072, rb2T + (size_t)l*4096,
        MUI, TV, N);
    k_mix2<<<ablk16, 256, 0, stream>>>(q, mu, dq, MUI, TV,
        mixW1 + (size_t)l*128*64, mixb1 + (size_t)l*64,
        mixW2 + (size_t)l*64*192, mixb2 + (size_t)l*192,
        muMixW + (size_t)l*64*128, N);
  }

  hipMemcpyAsync(d_out, q, (size_t)N*64*sizeof(float), hipMemcpyDeviceToDevice, stream);
  hipMemcpyAsync((float*)d_out + (size_t)N*64, mu, (size_t)N*384*sizeof(float),
                 hipMemcpyDeviceToDevice, stream);
}

// Round 8
// 696.830 us; speedup vs baseline: 2.7268x; 1.0640x over previous
//
#include <hip/hip_runtime.h>
#include <math.h>

#define FD 64
#define NRBF 20
#define CUT 5.0f
#define EPSV 1e-8f
#define PI_F 3.14159265358979f

__device__ __forceinline__ float wredsum(float v){
#pragma unroll
  for (int m = 32; m >= 1; m >>= 1) v += __shfl_xor(v, m, 64);
  return v;
}
__device__ __forceinline__ float wredmax(float v){
#pragma unroll
  for (int m = 32; m >= 1; m >>= 1) v = fmaxf(v, __shfl_xor(v, m, 64));
  return v;
}
__device__ __forceinline__ float silu_f(float x){ return x * (1.0f / (1.0f + __expf(-x))); }

// ---- K0: per-pair precompute: dir(3), fcut(1), phi*fcut(20) -> 24 floats ----
__global__ __launch_bounds__(256) void k_pairprep(const float* __restrict__ Rij,
                                                  float* __restrict__ pair, int P)
{
  int p = blockIdx.x * blockDim.x + threadIdx.x;
  if (p >= P) return;
  float rx = Rij[3*p+0], ry = Rij[3*p+1], rz = Rij[3*p+2];
  float d = sqrtf(rx*rx + ry*ry + rz*rz);
  float inv = 1.0f / d;
  float fc = (d < CUT) ? 0.5f * (__cosf(PI_F * d / CUT) + 1.0f) : 0.0f;
  float* pr = pair + (size_t)p * 24;
  pr[0] = rx*inv; pr[1] = ry*inv; pr[2] = rz*inv; pr[3] = fc;
  const float width = CUT / (float)(NRBF - 1);
#pragma unroll
  for (int r = 0; r < NRBF; ++r){
    float t = (d - width * (float)r) / width;
    pr[4+r] = __expf(-0.5f * t * t) * fc;
  }
}

// ---- CSR build: histogram, scan, scatter ----
__global__ __launch_bounds__(256) void k_count(const int* __restrict__ idx_i,
                                               int* __restrict__ cnt, int P)
{
  int p = blockIdx.x * blockDim.x + threadIdx.x;
  if (p < P) atomicAdd(&cnt[idx_i[p]], 1);
}

__global__ __launch_bounds__(1024) void k_scan(const int* __restrict__ cnt,
                                               int* __restrict__ start,
                                               int* __restrict__ cursor, int N)
{
  __shared__ int part[1024];
  int t = threadIdx.x;
  int chunk = (N + 1023) / 1024;
  int lo = t * chunk, hi = lo + chunk; if (hi > N) hi = N;
  int s = 0;
  for (int i = lo; i < hi; ++i) s += cnt[i];
  part[t] = s;
  __syncthreads();
  for (int off = 1; off < 1024; off <<= 1){
    int v = 0;
    if (t >= off) v = part[t - off];
    __syncthreads();
    if (t >= off) part[t] += v;
    __syncthreads();
  }
  int run = (t == 0) ? 0 : part[t-1];
  for (int i = lo; i < hi; ++i){ start[i] = run; cursor[i] = run; run += cnt[i]; }
  if (t == 1023) start[N] = run;
}

__global__ __launch_bounds__(256) void k_scatter(const int* __restrict__ idx_i,
                                                 int* __restrict__ cursor,
                                                 int* __restrict__ elist, int P)
{
  int p = blockIdx.x * blockDim.x + threadIdx.x;
  if (p < P){
    int pos = atomicAdd(&cursor[idx_i[p]], 1);
    elist[pos] = p;
  }
}

// ---- transpose rec_W2 -> swizzled bf16 rW2S; rb2 -> rb2T[l][c][f] (f32) ----
// ushort index t: km=t&7, slot=(t>>3)&3, f=(t>>5)&63, c=(t>>11)&63, l=t>>17
// stored k = ((slot ^ ((f>>1)&3))<<3) | km
__global__ __launch_bounds__(256) void k_transpose_w(const float* __restrict__ rW2,
                                                     const float* __restrict__ rb2,
                                                     unsigned short* __restrict__ rW2S,
                                                     float* __restrict__ rb2T)
{
  int t = blockIdx.x * blockDim.x + threadIdx.x;
  if (t < 2*64*64*32){
    int km   = t & 7;
    int slot = (t >> 3) & 3;
    int f    = (t >> 5) & 63;
    int c    = (t >> 11) & 63;
    int l    = t >> 17;
    int k    = ((slot ^ ((f >> 1) & 3)) << 3) | km;
    float v = rW2[((size_t)(l*32 + k))*4096 + f*64 + c];
    unsigned int u = __float_as_uint(v);
    unsigned int r = (u + 0x7fffu + ((u >> 16) & 1u)) >> 16;   // RNE to bf16
    rW2S[t] = (unsigned short)r;
  }
  if (t < 2*64*64){
    int f = t & 63, c = (t >> 6) & 63, l = t >> 12;
    rb2T[t] = rb2[(size_t)l*4096 + f*64 + c];
  }
}

// ---- K_init: q = embed[Z] ----
__global__ __launch_bounds__(256) void k_init_q(const int* __restrict__ Z,
                                                const float* __restrict__ embed,
                                                float* __restrict__ q, int Ntot)
{
  int t = blockIdx.x * blockDim.x + threadIdx.x;
  if (t >= Ntot * FD) return;
  int n = t >> 6, f = t & 63;
  q[t] = embed[Z[n]*FD + f];
}

// ---- K1 v2: per-atom pre. 16 atoms/block (4 per wave), weights LDS-staged. ----
__global__ __launch_bounds__(256) void k_atom_pre(
    const float* __restrict__ q, const float* __restrict__ mu,
    const float* __restrict__ cW1, const float* __restrict__ cb1,
    const float* __restrict__ cW2, const float* __restrict__ cb2,
    const float* __restrict__ pW1, const float* __restrict__ pb1,
    const float* __restrict__ pW2, const float* __restrict__ pb2,
    float* __restrict__ XCV, int Ntot)
{
  __shared__ float wbuf[12288];     // 48 KB
  __shared__ float qs[16][64];      // 4 KB
  __shared__ float sbuf[16][128];   // 8 KB
  __shared__ float h1s[16][64];     // 4 KB
  __shared__ float hcs[16][32];     // 2 KB
  int t = threadIdx.x;
  int w = t >> 6, f = t & 63;
  int base = blockIdx.x * 16;
  const int aw = w * 4;
  float4* wt4 = (float4*)wbuf;

  float m0a[4], m1a[4], m2a[4], m0b[4], m1b[4], m2b[4];
#pragma unroll
  for (int s = 0; s < 4; ++s){
    int a = aw + s;
    int n = base + a; if (n >= Ntot) n = Ntot - 1;
    qs[a][f] = q[(size_t)n*64 + f];
    const float* mun = mu + (size_t)n * 384;
    m0a[s] = mun[0*128 + f];      m1a[s] = mun[1*128 + f];      m2a[s] = mun[2*128 + f];
    m0b[s] = mun[0*128 + 64 + f]; m1b[s] = mun[1*128 + 64 + f]; m2b[s] = mun[2*128 + 64 + f];
    sbuf[a][f]      = sqrtf(m0a[s]*m0a[s] + m1a[s]*m1a[s] + m2a[s]*m2a[s] + EPSV);
    sbuf[a][64 + f] = sqrtf(m0b[s]*m0b[s] + m1b[s]*m1b[s] + m2b[s]*m2b[s] + EPSV);
  }
  // stage cW1 (64x64 = 16 KB)
#pragma unroll
  for (int i = 0; i < 4; ++i) wt4[t + i*256] = ((const float4*)cW1)[t + i*256];
  __syncthreads();

  float hacc[4];
#pragma unroll
  for (int s = 0; s < 4; ++s) hacc[s] = cb1[f];
  for (int k = 0; k < 64; ++k){
    float wv = wbuf[k*64 + f];
#pragma unroll
    for (int s = 0; s < 4; ++s) hacc[s] = fmaf(qs[aw + s][k], wv, hacc[s]);
  }
#pragma unroll
  for (int s = 0; s < 4; ++s) h1s[aw + s][f] = silu_f(hacc[s]);

  // stage cW2 (64x192 = 48 KB)
  __syncthreads();
#pragma unroll
  for (int i = 0; i < 12; ++i) wt4[t + i*256] = ((const float4*)cW2)[t + i*256];
  __syncthreads();

  float x0[4], x1[4], x2[4];
#pragma unroll
  for (int s = 0; s < 4; ++s){ x0[s] = cb2[f]; x1[s] = cb2[64+f]; x2[s] = cb2[128+f]; }
  for (int k = 0; k < 64; ++k){
    float u0 = wbuf[k*192 + f];
    float u1 = wbuf[k*192 + 64 + f];
    float u2 = wbuf[k*192 + 128 + f];
#pragma unroll
    for (int s = 0; s < 4; ++s){
      float h = h1s[aw + s][k];
      x0[s] = fmaf(h, u0, x0[s]); x1[s] = fmaf(h, u1, x1[s]); x2[s] = fmaf(h, u2, x2[s]);
    }
  }
#pragma unroll
  for (int s = 0; s < 4; ++s){
    int n = base + aw + s;
    if (n < Ntot){
      float* Xn = XCV + (size_t)n*384;
      Xn[f] = x0[s]; Xn[64+f] = x1[s]; Xn[128+f] = x2[s];
    }
  }

  // stage pW1 (128x32 = 16 KB @0) + pW2 (32x64 = 8 KB @4096)
  __syncthreads();
#pragma unroll
  for (int i = 0; i < 4; ++i) wt4[t + i*256] = ((const float4*)pW1)[t + i*256];
#pragma unroll
  for (int i = 0; i < 2; ++i) wt4[1024 + t + i*256] = ((const float4*)pW2)[t + i*256];
  __syncthreads();

  // compress hidden: two lane-split passes, 2 atoms per pass
  int ki = f & 31;
#pragma unroll
  for (int p = 0; p < 2; ++p){
    int a_h = aw + p*2 + (f >> 5);
    float ah = pb1[ki];
#pragma unroll 4
    for (int c = 0; c < 128; ++c) ah = fmaf(sbuf[a_h][c], wbuf[c*32 + ki], ah);
    hcs[a_h][ki] = fmaxf(ah, 0.0f);
  }

  float logit[4];
#pragma unroll
  for (int s = 0; s < 4; ++s) logit[s] = pb2[f];
  for (int k = 0; k < 32; ++k){
    float wv = wbuf[4096 + k*64 + f];
#pragma unroll
    for (int s = 0; s < 4; ++s) logit[s] = fmaf(hcs[aw + s][k], wv, logit[s]);
  }
#pragma unroll
  for (int s = 0; s < 4; ++s){
    float mx = wredmax(logit[s]);
    float e  = __expf(logit[s] - mx);
    float se = wredsum(e);
    float wt = e / se;
    float v0 = wredsum(m0a[s] + m0b[s]);
    float v1 = wredsum(m1a[s] + m1b[s]);
    float v2 = wredsum(m2a[s] + m2b[s]);
    int n = base + aw + s;
    if (n < Ntot){
      float* cvn = XCV + (size_t)n*384 + 192;
      cvn[f] = v0 * wt; cvn[64+f] = v1 * wt; cvn[128+f] = v2 * wt;
    }
  }
}

// ---- K2: gather form, unroll-2. One wave per atom i; no atomics. ----
__global__ __launch_bounds__(256) void k_gather(
    const float* __restrict__ pair, const int* __restrict__ elist,
    const int* __restrict__ start, const int* __restrict__ idx_j,
    const float* __restrict__ fW, const float* __restrict__ fb,
    const float* __restrict__ XCV,
    float* __restrict__ dq, float* __restrict__ dmu, int l, int Ntot)
{
  int w = threadIdx.x >> 6;
  int f = threadIdx.x & 63;
  int i = blockIdx.x * 4 + w;
  if (i >= Ntot) return;
  const int col = l * 192;

  float fw0[NRBF], fw1[NRBF], fw2[NRBF];
#pragma unroll
  for (int r = 0; r < NRBF; ++r){
    const float* fr = fW + r*384 + col;
    fw0[r] = fr[f]; fw1[r] = fr[64 + f]; fw2[r] = fr[128 + f];
  }
  float fb0 = fb[col + f], fb1 = fb[col + 64 + f], fb2 = fb[col + 128 + f];

  float dqa = 0.f, dm0 = 0.f, dm1 = 0.f, dm2 = 0.f;
  int e0 = start[i], e1 = start[i+1];
  int e = e0;
  for (; e + 2 <= e1; e += 2){
    int pA = elist[e], pB = elist[e+1];
    int jA = idx_j[pA], jB = idx_j[pB];
    const float4* prA = (const float4*)(pair + (size_t)pA * 24);
    const float4* prB = (const float4*)(pair + (size_t)pB * 24);
    float4 A0=prA[0],A1=prA[1],A2=prA[2],A3=prA[3],A4=prA[4],A5=prA[5];
    float4 B0=prB[0],B1=prB[1],B2=prB[2],B3=prB[3],B4=prB[4],B5=prB[5];
    const float* xA = XCV + (size_t)jA * 384;
    const float* xB = XCV + (size_t)jB * 384;
    float xA0=xA[f], xA1=xA[64+f], xA2=xA[128+f], cA0=xA[192+f], cA1=xA[256+f], cA2=xA[320+f];
    float xB0=xB[f], xB1=xB[64+f], xB2=xB[128+f], cB0=xB[192+f], cB1=xB[256+f], cB2=xB[320+f];
    float phA[NRBF] = {A1.x,A1.y,A1.z,A1.w, A2.x,A2.y,A2.z,A2.w,
                       A3.x,A3.y,A3.z,A3.w, A4.x,A4.y,A4.z,A4.w,
                       A5.x,A5.y,A5.z,A5.w};
    float phB[NRBF] = {B1.x,B1.y,B1.z,B1.w, B2.x,B2.y,B2.z,B2.w,
                       B3.x,B3.y,B3.z,B3.w, B4.x,B4.y,B4.z,B4.w,
                       B5.x,B5.y,B5.z,B5.w};
    float wA0=fb0*A0.w, wA1=fb1*A0.w, wA2=fb2*A0.w;
    float wB0=fb0*B0.w, wB1=fb1*B0.w, wB2=fb2*B0.w;
#pragma unroll
    for (int r = 0; r < NRBF; ++r){
      wA0 = fmaf(phA[r], fw0[r], wA0);
      wA1 = fmaf(phA[r], fw1[r], wA1);
      wA2 = fmaf(phA[r], fw2[r], wA2);
      wB0 = fmaf(phB[r], fw0[r], wB0);
      wB1 = fmaf(phB[r], fw1[r], wB1);
      wB2 = fmaf(phB[r], fw2[r], wB2);
    }
    dqa = fmaf(xA0, wA0, dqa);
    float dmRA = xA1 * wA1, dmmA = xA2 * wA2;
    dm0 = fmaf(dmRA, A0.x, fmaf(dmmA, cA0, dm0));
    dm1 = fmaf(dmRA, A0.y, fmaf(dmmA, cA1, dm1));
    dm2 = fmaf(dmRA, A0.z, fmaf(dmmA, cA2, dm2));
    dqa = fmaf(xB0, wB0, dqa);
    float dmRB = xB1 * wB1, dmmB = xB2 * wB2;
    dm0 = fmaf(dmRB, B0.x, fmaf(dmmB, cB0, dm0));
    dm1 = fmaf(dmRB, B0.y, fmaf(dmmB, cB1, dm1));
    dm2 = fmaf(dmRB, B0.z, fmaf(dmmB, cB2, dm2));
  }
  if (e < e1){
    int p = elist[e];
    int j = idx_j[p];
    const float4* pr4 = (const float4*)(pair + (size_t)p * 24);
    float4 v0 = pr4[0], v1 = pr4[1], v2 = pr4[2], v3 = pr4[3], v4 = pr4[4], v5 = pr4[5];
    const float* xj = XCV + (size_t)j * 384;
    float ph[NRBF] = {v1.x,v1.y,v1.z,v1.w, v2.x,v2.y,v2.z,v2.w,
                      v3.x,v3.y,v3.z,v3.w, v4.x,v4.y,v4.z,v4.w,
                      v5.x,v5.y,v5.z,v5.w};
    float w0 = fb0 * v0.w, w1 = fb1 * v0.w, w2 = fb2 * v0.w;
#pragma unroll
    for (int r = 0; r < NRBF; ++r){
      w0 = fmaf(ph[r], fw0[r], w0);
      w1 = fmaf(ph[r], fw1[r], w1);
      w2 = fmaf(ph[r], fw2[r], w2);
    }
    dqa = fmaf(xj[f], w0, dqa);
    float dmR = xj[64 + f]  * w1;
    float dmm = xj[128 + f] * w2;
    dm0 = fmaf(dmR, v0.x, fmaf(dmm, xj[192 + f], dm0));
    dm1 = fmaf(dmR, v0.y, fmaf(dmm, xj[256 + f], dm1));
    dm2 = fmaf(dmR, v0.z, fmaf(dmm, xj[320 + f], dm2));
  }
  dq[(size_t)i*64 + f] = dqa;
  float* dmn = dmu + (size_t)i*192;
  dmn[f] = dm0; dmn[64 + f] = dm1; dmn[128 + f] = dm2;
}

// ---- K3a v4: tv with bf16 weight tiles. 512 threads, 16 atoms/block (2/wave).
// 8-c tiles (32 KB bf16), unpack 8 weights per ds_read_b128. ----
__global__ __launch_bounds__(512) void k_tv(
    const float* __restrict__ dmuA, const float* __restrict__ XCV,
    const float* __restrict__ rW1, const float* __restrict__ rb1,
    const unsigned short* __restrict__ rW2S, const float* __restrict__ rb2Tl,
    float* __restrict__ MUI, float* __restrict__ TV, int Ntot)
{
  __shared__ float mus[16][3][64];  // 12 KB
  __shared__ float svs[16][64];     // 4 KB
  __shared__ float4 wt4[2048];      // 32 KB: 8 c x 64 f x 32 bf16
  __shared__ float rbt[8][64];      // 2 KB
  int t = threadIdx.x;
  int w = t >> 6, f = t & 63;
  int base = blockIdx.x * 16;

#pragma unroll
  for (int s = 0; s < 2; ++s){
    int a = w*2 + s;
    int n = base + a; bool ok = (n < Ntot); if (!ok) n = Ntot - 1;
    const float* dmn = dmuA + (size_t)n*192;
    const float* cvn = XCV  + (size_t)n*384 + 192;
    float m0 = dmn[f]       + cvn[f];
    float m1 = dmn[64 + f]  + cvn[64 + f];
    float m2 = dmn[128 + f] + cvn[128 + f];
    mus[a][0][f] = m0; mus[a][1][f] = m1; mus[a][2][f] = m2;
    svs[a][f] = sqrtf(m0*m0 + m1*m1 + m2*m2 + EPSV);
    if (ok){
      float* mo = MUI + (size_t)n*192;
      mo[f] = m0; mo[64+f] = m1; mo[128+f] = m2;
    }
  }
  __syncthreads();

  int ki = f & 31;
  int a_h = w*2 + (f >> 5);
  float ah = rb1[ki];
#pragma unroll
  for (int c = 0; c < 64; ++c) ah = fmaf(svs[a_h][c], rW1[c*32 + ki], ah);
  ah = fmaxf(ah, 0.0f);
  float hreg[2][32];
#pragma unroll
  for (int k = 0; k < 32; ++k){
    hreg[0][k] = __shfl(ah, k, 64);
    hreg[1][k] = __shfl(ah, 32 + k, 64);
  }

  const int a0 = w*2, a1 = a0 + 1;
  float mf00 = mus[a0][0][f], mf01 = mus[a0][1][f], mf02 = mus[a0][2][f];
  float mf10 = mus[a1][0][f], mf11 = mus[a1][1][f], mf12 = mus[a1][2][f];
  float tv00=0,tv01=0,tv02=0, tv10=0,tv11=0,tv12=0;
  const int sw2 = (f >> 1) & 3;

  for (int ct = 0; ct < 8; ++ct){
    __syncthreads();
    const float4* src = (const float4*)rW2S + (size_t)ct*2048;
#pragma unroll
    for (int i = 0; i < 4; ++i) wt4[t + i*512] = src[t + i*512];
    if (t < 128) ((float4*)rbt)[t] = ((const float4*)(rb2Tl + ct*512))[t];
    __syncthreads();

#pragma unroll
    for (int cc = 0; cc < 8; ++cc){
      int c = ct*8 + cc;
      float u00 = mus[a0][0][c], u01 = mus[a0][1][c], u02 = mus[a0][2][c];
      float u10 = mus[a1][0][c], u11 = mus[a1][1][c], u12 = mus[a1][2][c];
      float g0 = u00*mf00 + u01*mf01 + u02*mf02;
      float g1 = u10*mf10 + u11*mf11 + u12*mf12;
      float acc0 = rbt[cc][f];
      float acc1 = acc0;
      const uint4* wrow = reinterpret_cast<const uint4*>(&wt4[(cc*64 + f)*4]);
#pragma unroll
      for (int kq = 0; kq < 4; ++kq){
        uint4 u = wrow[kq ^ sw2];
        int k0 = kq*8;
        float w0 = __uint_as_float(u.x << 16);
        float w1 = __uint_as_float(u.x & 0xffff0000u);
        float w2 = __uint_as_float(u.y << 16);
        float w3 = __uint_as_float(u.y & 0xffff0000u);
        float w4 = __uint_as_float(u.z << 16);
        float w5 = __uint_as_float(u.z & 0xffff0000u);
        float w6 = __uint_as_float(u.w << 16);
        float w7 = __uint_as_float(u.w & 0xffff0000u);
        acc0 = fmaf(hreg[0][k0+0], w0, acc0);
        acc0 = fmaf(hreg[0][k0+1], w1, acc0);
        acc0 = fmaf(hreg[0][k0+2], w2, acc0);
        acc0 = fmaf(hreg[0][k0+3], w3, acc0);
        acc0 = fmaf(hreg[0][k0+4], w4, acc0);
        acc0 = fmaf(hreg[0][k0+5], w5, acc0);
        acc0 = fmaf(hreg[0][k0+6], w6, acc0);
        acc0 = fmaf(hreg[0][k0+7], w7, acc0);
        acc1 = fmaf(hreg[1][k0+0], w0, acc1);
        acc1 = fmaf(hreg[1][k0+1], w1, acc1);
        acc1 = fmaf(hreg[1][k0+2], w2, acc1);
        acc1 = fmaf(hreg[1][k0+3], w3, acc1);
        acc1 = fmaf(hreg[1][k0+4], w4, acc1);
        acc1 = fmaf(hreg[1][k0+5], w5, acc1);
        acc1 = fmaf(hreg[1][k0+6], w6, acc1);
        acc1 = fmaf(hreg[1][k0+7], w7, acc1);
      }
      float mm0 = acc0 * g0, mm1 = acc1 * g1;
      tv00 = fmaf(u00, mm0, tv00); tv01 = fmaf(u01, mm0, tv01); tv02 = fmaf(u02, mm0, tv02);
      tv10 = fmaf(u10, mm1, tv10); tv11 = fmaf(u11, mm1, tv11); tv12 = fmaf(u12, mm1, tv12);
    }
  }

  int n0 = base + a0, n1 = base + a1;
  if (n0 < Ntot){
    float* tvp = TV + (size_t)n0*192;
    tvp[f] = tv00; tvp[64+f] = tv01; tvp[128+f] = tv02;
  }
  if (n1 < Ntot){
    float* tvp = TV + (size_t)n1*192;
    tvp[f] = tv10; tvp[64+f] = tv11; tvp[128+f] = tv12;
  }
}

// ---- K3b: mixing tail. 16 atoms/block (4 per wave), weights LDS-staged. ----
__global__ __launch_bounds__(256) void k_mix2(
    float* __restrict__ q, float* __restrict__ mu,
    const float* __restrict__ dq, const float* __restrict__ MUI, const float* __restrict__ TV,
    const float* __restrict__ mW1, const float* __restrict__ mb1,
    const float* __restrict__ mW2, const float* __restrict__ mb2,
    const float* __restrict__ Wm, int Ntot)
{
  __shared__ float wbuf[12288];     // 48 KB
  __shared__ float mua[16][3][64];  // 12 KB
  __shared__ float ava[16][128];    // 8 KB
  __shared__ float h2a[16][64];     // 4 KB
  int t = threadIdx.x;
  int w = t >> 6, f = t & 63;
  int base = blockIdx.x * 16;
  const int aw = w * 4;
  float4* wt4 = (float4*)wbuf;

  float qv[4], m0[4], m1[4], m2[4];
#pragma unroll
  for (int s = 0; s < 4; ++s){
    int a = aw + s;
    int n = base + a; if (n >= Ntot) n = Ntot - 1;
    qv[s] = q[(size_t)n*64 + f] + dq[(size_t)n*64 + f];
    const float* mi = MUI + (size_t)n*192;
    m0[s] = mi[f]; m1[s] = mi[64 + f]; m2[s] = mi[128 + f];
    mua[a][0][f] = m0[s]; mua[a][1][f] = m1[s]; mua[a][2][f] = m2[s];
  }

#pragma unroll
  for (int i = 0; i < 8; ++i) wt4[t + i*256] = ((const float4*)Wm)[t + i*256];
  __syncthreads();

  float V0[4]={0,0,0,0}, V1[4]={0,0,0,0}, V2[4]={0,0,0,0};
  float W0[4]={0,0,0,0}, W1[4]={0,0,0,0}, W2[4]={0,0,0,0};
  for (int k = 0; k < 64; ++k){
    float wv = wbuf[k*128 + f];
    float ww = wbuf[k*128 + 64 + f];
#pragma unroll
    for (int s = 0; s < 4; ++s){
      int a = aw + s;
      float b0 = mua[a][0][k], b1 = mua[a][1][k], b2 = mua[a][2][k];
      V0[s] = fmaf(b0, wv, V0[s]); V1[s] = fmaf(b1, wv, V1[s]); V2[s] = fmaf(b2, wv, V2[s]);
      W0[s] = fmaf(b0, ww, W0[s]); W1[s] = fmaf(b1, ww, W1[s]); W2[s] = fmaf(b2, ww, W2[s]);
    }
  }
  float dot[4];
#pragma unroll
  for (int s = 0; s < 4; ++s){
    int a = aw + s;
    ava[a][f] = qv[s];
    ava[a][64 + f] = sqrtf(V0[s]*V0[s] + V1[s]*V1[s] + V2[s]*V2[s] + EPSV);
    dot[s] = V0[s]*W0[s] + V1[s]*W1[s] + V2[s]*W2[s];
  }

  __syncthreads();
#pragma unroll
  for (int i = 0; i < 8; ++i) wt4[t + i*256] = ((const float4*)mW1)[t + i*256];
  __syncthreads();

  float acc[4];
#pragma unroll
  for (int s = 0; s < 4; ++s) acc[s] = mb1[f];
  for (int k = 0; k < 128; ++k){
    float wv = wbuf[k*64 + f];
#pragma unroll
    for (int s = 0; s < 4; ++s) acc[s] = fmaf(ava[aw + s][k], wv, acc[s]);
  }
#pragma unroll
  for (int s = 0; s < 4; ++s) h2a[aw + s][f] = silu_f(acc[s]);

  __syncthreads();
#pragma unroll
  for (int i = 0; i < 12; ++i) wt4[t + i*256] = ((const float4*)mW2)[t + i*256];
  __syncthreads();

  float y0[4], y1[4], y2[4];
#pragma unroll
  for (int s = 0; s < 4; ++s){ y0[s] = mb2[f]; y1[s] = mb2[64+f]; y2[s] = mb2[128+f]; }
  for (int k = 0; k < 64; ++k){
    float u0 = wbuf[k*192 + f];
    float u1 = wbuf[k*192 + 64 + f];
    float u2 = wbuf[k*192 + 128 + f];
#pragma unroll
    for (int s = 0; s < 4; ++s){
      float h = h2a[aw + s][k];
      y0[s] = fmaf(h, u0, y0[s]); y1[s] = fmaf(h, u1, y1[s]); y2[s] = fmaf(h, u2, y2[s]);
    }
  }

#pragma unroll
  for (int s = 0; s < 4; ++s){
    int n = base + aw + s;
    if (n < Ntot){
      q[(size_t)n*64 + f] = qv[s] + y0[s] + y2[s]*dot[s];
      const float* tvp = TV + (size_t)n*192;
      float* mun = mu + (size_t)n*384;
      mun[0*128 + f] = fmaf(y1[s], W0[s], m0[s]); mun[0*128 + 64 + f] = tvp[f];
      mun[1*128 + f] = fmaf(y1[s], W1[s], m1[s]); mun[1*128 + 64 + f] = tvp[64+f];
      mun[2*128 + f] = fmaf(y1[s], W2[s], m2[s]); mun[2*128 + 64 + f] = tvp[128+f];
    }
  }
}

extern "C" void kernel_launch(void* const* d_in, const int* in_sizes, int n_in,
                              void* d_out, int out_size, void* d_ws, size_t ws_size,
                              hipStream_t stream)
{
  const int*   Z      = (const int*)  d_in[0];
  const float* Rij    = (const float*)d_in[1];
  const int*   idx_i  = (const int*)  d_in[2];
  const int*   idx_j  = (const int*)  d_in[3];
  const float* embed  = (const float*)d_in[5];
  const float* fW     = (const float*)d_in[6];
  const float* fb     = (const float*)d_in[7];
  const float* ctxW1  = (const float*)d_in[8];
  const float* ctxb1  = (const float*)d_in[9];
  const float* ctxW2  = (const float*)d_in[10];
  const float* ctxb2  = (const float*)d_in[11];
  const float* compW1 = (const float*)d_in[12];
  const float* compb1 = (const float*)d_in[13];
  const float* compW2 = (const float*)d_in[14];
  const float* compb2 = (const float*)d_in[15];
  const float* recW1  = (const float*)d_in[16];
  const float* recb1  = (const float*)d_in[17];
  const float* recW2  = (const float*)d_in[18];
  const float* recb2  = (const float*)d_in[19];
  const float* mixW1  = (const float*)d_in[20];
  const float* mixb1  = (const float*)d_in[21];
  const float* mixW2  = (const float*)d_in[22];
  const float* mixb2  = (const float*)d_in[23];
  const float* muMixW = (const float*)d_in[24];

  const int N = in_sizes[0];
  const int P = in_sizes[1] / 3;

  float* ws    = (float*)d_ws;
  float* pair  = ws;                         // P*24
  float* q     = pair  + (size_t)P*24;       // N*64
  float* mu    = q     + (size_t)N*64;       // N*384
  float* XCV   = mu    + (size_t)N*384;      // N*384
  float* dq    = XCV   + (size_t)N*384;      // N*64
  float* dmu   = dq    + (size_t)N*64;       // N*192
  float* rW2Sf = dmu   + (size_t)N*192;      // bf16 512KB (occupies 131072 floats)
  float* rb2T  = rW2Sf + (size_t)131072;     // 8192
  float* TV    = rb2T  + (size_t)8192;       // N*192
  float* MUI   = TV    + (size_t)N*192;      // N*192
  int*   cnt    = (int*)(MUI + (size_t)N*192); // N
  int*   startA = cnt    + N;                  // N+1
  int*   cursor = startA + (N + 1);            // N
  int*   elist  = cursor + N;                  // P
  unsigned short* rW2S = (unsigned short*)rW2Sf;

  k_pairprep<<<(P + 255)/256, 256, 0, stream>>>(Rij, pair, P);
  k_transpose_w<<<(2*64*64*32 + 255)/256, 256, 0, stream>>>(recW2, recb2, rW2S, rb2T);
  hipMemsetAsync(mu, 0, (size_t)N*384*sizeof(float), stream);
  hipMemsetAsync(cnt, 0, (size_t)N*sizeof(int), stream);
  k_init_q<<<(N*FD + 255)/256, 256, 0, stream>>>(Z, embed, q, N);

  // CSR build (idx_i fixed across layers)
  k_count<<<(P + 255)/256, 256, 0, stream>>>(idx_i, cnt, P);
  k_scan<<<1, 1024, 0, stream>>>(cnt, startA, cursor, N);
  k_scatter<<<(P + 255)/256, 256, 0, stream>>>(idx_i, cursor, elist, P);

  const int ablk4  = (N + 3) / 4;
  const int ablk16 = (N + 15) / 16;
  for (int l = 0; l < 2; ++l){
    k_atom_pre<<<ablk16, 256, 0, stream>>>(q, mu,
        ctxW1 + (size_t)l*64*64,  ctxb1 + (size_t)l*64,
        ctxW2 + (size_t)l*64*192, ctxb2 + (size_t)l*192,
        compW1 + (size_t)l*128*32, compb1 + (size_t)l*32,
        compW2 + (size_t)l*32*64,  compb2 + (size_t)l*64,
        XCV, N);
    k_gather<<<ablk4, 256, 0, stream>>>(pair, elist, startA, idx_j, fW, fb, XCV,
        dq, dmu, l, N);
    k_tv<<<ablk16, 512, 0, stream>>>(dmu, XCV,
        recW1 + (size_t)l*64*32, recb1 + (size_t)l*32,
        rW2S + (size_t)l*131072, rb2T + (size_t)l*4096,
        MUI, TV, N);
    k_mix2<<<ablk16, 256, 0, stream>>>(q, mu, dq, MUI, TV,
        mixW1 + (size_t)l*128*64, mixb1 + (size_t)l*64,
        mixW2 + (size_t)l*64*192, mixb2 + (size_t)l*192,
        muMixW + (size_t)l*64*128, N);
  }

  hipMemcpyAsync(d_out, q, (size_t)N*64*sizeof(float), hipMemcpyDeviceToDevice, stream);
  hipMemcpyAsync((float*)d_out + (size_t)N*64, mu, (size_t)N*384*sizeof(float),
                 hipMemcpyDeviceToDevice, stream);
}